// Round 2
// baseline (598.860 us; speedup 1.0000x reference)
//
#include <hip/hip_runtime.h>

typedef unsigned short ushort_t;
typedef __bf16 b16x8 __attribute__((ext_vector_type(8)));
typedef float f32x4 __attribute__((ext_vector_type(4)));
typedef unsigned short u16x8 __attribute__((ext_vector_type(8)));

#define DEVINL __device__ __forceinline__

constexpr int B = 16, S = 512, F = 1024;
constexpr int M_ROWS = B * S;                    // 8192
constexpr size_t NX = (size_t)M_ROWS * F;        // 8,388,608 elems per modality
constexpr size_t NW = (size_t)F * (2 * F);       // 2,097,152 elems per branch (WT: 1024x2048)
constexpr size_t NSC = (size_t)3 * B * S * S;    // 12,582,912 score elems

// ---------- bf16 helpers (RNE) ----------
DEVINL ushort_t f2bf(float f) {
  unsigned int u = __builtin_bit_cast(unsigned int, f);
  u += 0x7FFFu + ((u >> 16) & 1u);
  return (ushort_t)(u >> 16);
}
DEVINL float bf2f(ushort_t h) {
  unsigned int u = ((unsigned int)h) << 16;
  return __builtin_bit_cast(float, u);
}

// ---------- async global->LDS (16B per lane) ----------
DEVINL void gload_lds16(const void* g, void* l) {
  __builtin_amdgcn_global_load_lds(
      (__attribute__((address_space(1))) void*)(g),
      (__attribute__((address_space(3))) void*)(l), 16, 0, 0);
}

DEVINL f32x4 mfma16(b16x8 a, b16x8 b, f32x4 c) {
  return __builtin_amdgcn_mfma_f32_16x16x32_bf16(a, b, c, 0, 0, 0);
}

// ---------- 2-phase helpers (used by pv_gemm only) ----------
DEVINL void stage_tile(ushort_t* lds, const ushort_t* src, int ld, int tid) {
  int wave = tid >> 6;
#pragma unroll
  for (int it = 0; it < 2; ++it) {
    int c = it * 256 + tid;
    const ushort_t* g = src + (size_t)(c >> 2) * ld + (c & 3) * 8;
    ushort_t* l = lds + (size_t)(it * 256 + wave * 64) * 8;
    gload_lds16(g, l);
  }
}
DEVINL b16x8 frag_ld(const ushort_t* lds, int rb, int lane) {
  return *(const b16x8*)(lds + (size_t)(rb + (lane & 15)) * 32 + (lane >> 4) * 8);
}

// ================== 8-phase split-bf16 GEMM core ==================
// C[256x128] = A[256xK] * B^T (B row-major [128-cols x K]), 3-MFMA Ootomo split.
// 8 waves (4M x 2N), wave-tile 64x64 = 4x4 frags of 16x16x32.
// LDS: 3 buffers x {Ah[256][32], Al, Bh[128][32], Bl} = 3 x 48KB.
// Counted vmcnt(6): 6 loads/wave/step, 2-step prefetch depth.
template <int KSTEPS, int KSPLIT>
DEVINL void gemm8p_core(const ushort_t* __restrict__ a1h, const ushort_t* __restrict__ a1l,
                        const ushort_t* __restrict__ a2h, const ushort_t* __restrict__ a2l, int lda,
                        const ushort_t* __restrict__ bh, const ushort_t* __restrict__ bl, int ldb,
                        ushort_t* lds, int tid, f32x4 (&acc)[4][4]) {
  constexpr int BUFE = 24576, ALO = 8192, BHI = 16384, BLO = 20480;
  const int lane = tid & 63, w = tid >> 6;
  const int wr = (w >> 1) * 64, wc = (w & 1) * 64;
  // staging: lane l -> row base+(l>>2), k-chunk (l&3) XOR-swizzled by ((row>>1)&3)=(l>>3)&3
  const int scol = (((lane & 3) ^ ((lane >> 3) & 3)) * 8);
  const size_t aoff = (size_t)(w * 32 + (lane >> 2)) * lda + scol;
  const size_t boff = (size_t)(w * 16 + (lane >> 2)) * ldb + scol;
  // ds_read: row rb+(lane&15), logical chunk lane>>4 -> phys slot ^((row>>1)&3)
  const int foff = (lane & 15) * 32 + (((lane >> 4) ^ ((lane >> 1) & 3)) * 8);

  auto stA = [&](const ushort_t* x1, const ushort_t* x2, int region, int sb, int ks) {
    int k0 = ks * 32;
    const ushort_t* s =
        (((KSPLIT >= KSTEPS * 32) || (k0 < KSPLIT)) ? x1 : x2) + aoff + (k0 & (KSPLIT - 1));
    ushort_t* d = lds + sb * BUFE + region + w * 1024;   // wave-uniform base, HW adds lane*16B
    gload_lds16(s, d);
    gload_lds16(s + (size_t)16 * lda, d + 512);
  };
  auto stB = [&](const ushort_t* bb, int region, int sb, int ks) {
    const ushort_t* s = bb + boff + ks * 32;
    ushort_t* d = lds + sb * BUFE + region + w * 512;
    gload_lds16(s, d);
  };
  auto FR = [&](const ushort_t* base, int rb) -> b16x8 {
    return *(const b16x8*)(base + rb * 32 + foff);
  };

#define MM(i, j)                                         \
  do {                                                   \
    acc[i][j] = mfma16(rAh[i], rBh[j], acc[i][j]);       \
    acc[i][j] = mfma16(rAh[i], rBl[j], acc[i][j]);       \
    acc[i][j] = mfma16(rAl[i], rBh[j], acc[i][j]);       \
  } while (0)

  // prologue: stage steps 0 and 1 (issue order: all of step0 first)
  stA(a1h, a2h, 0, 0, 0); stA(a1l, a2l, ALO, 0, 0); stB(bh, BHI, 0, 0); stB(bl, BLO, 0, 0);
  stA(a1h, a2h, 0, 1, 1); stA(a1l, a2l, ALO, 1, 1); stB(bh, BHI, 1, 1); stB(bl, BLO, 1, 1);
  asm volatile("s_waitcnt vmcnt(6)" ::: "memory");   // step 0 landed
  asm volatile("s_barrier" ::: "memory");

  for (int t = 0; t < KSTEPS; ++t) {
    const int cb = t % 3, sb = (t + 2) % 3;
    const int ks = (t + 2) & (KSTEPS - 1);             // clamped tail keeps vmcnt math uniform
    const ushort_t* L = lds + cb * BUFE;
    b16x8 rAh[4], rAl[4], rBh[4], rBl[4];
    // ---- phase 0: A[0..1], B[0..1]; MFMA m01 x n01
    rAh[0] = FR(L, wr);        rAh[1] = FR(L, wr + 16);
    rAl[0] = FR(L + ALO, wr);  rAl[1] = FR(L + ALO, wr + 16);
    rBh[0] = FR(L + BHI, wc);  rBh[1] = FR(L + BHI, wc + 16);
    rBl[0] = FR(L + BLO, wc);  rBl[1] = FR(L + BLO, wc + 16);
    stA(a1h, a2h, 0, sb, ks);
    asm volatile("s_barrier" ::: "memory");
    asm volatile("s_waitcnt lgkmcnt(0)" ::: "memory");
    __builtin_amdgcn_s_setprio(1);
    MM(0, 0); MM(0, 1); MM(1, 0); MM(1, 1);
    __builtin_amdgcn_s_setprio(0);
    asm volatile("s_barrier" ::: "memory");
    // ---- phase 1: B[2..3]; MFMA m01 x n23
    rBh[2] = FR(L + BHI, wc + 32); rBh[3] = FR(L + BHI, wc + 48);
    rBl[2] = FR(L + BLO, wc + 32); rBl[3] = FR(L + BLO, wc + 48);
    stA(a1l, a2l, ALO, sb, ks);
    asm volatile("s_barrier" ::: "memory");
    asm volatile("s_waitcnt lgkmcnt(0)" ::: "memory");
    __builtin_amdgcn_s_setprio(1);
    MM(0, 2); MM(0, 3); MM(1, 2); MM(1, 3);
    __builtin_amdgcn_s_setprio(0);
    asm volatile("s_barrier" ::: "memory");
    // ---- phase 2: A[2..3]; MFMA m23 x n23
    rAh[2] = FR(L, wr + 32);       rAh[3] = FR(L, wr + 48);
    rAl[2] = FR(L + ALO, wr + 32); rAl[3] = FR(L + ALO, wr + 48);
    stB(bh, BHI, sb, ks);
    asm volatile("s_barrier" ::: "memory");
    asm volatile("s_waitcnt lgkmcnt(0)" ::: "memory");
    __builtin_amdgcn_s_setprio(1);
    MM(2, 2); MM(2, 3); MM(3, 2); MM(3, 3);
    __builtin_amdgcn_s_setprio(0);
    asm volatile("s_barrier" ::: "memory");
    // ---- phase 3: no reads; MFMA m23 x n01; counted vmcnt at step end
    stB(bl, BLO, sb, ks);
    asm volatile("s_barrier" ::: "memory");
    __builtin_amdgcn_s_setprio(1);
    MM(2, 0); MM(2, 1); MM(3, 0); MM(3, 1);
    __builtin_amdgcn_s_setprio(0);
    asm volatile("s_waitcnt vmcnt(6)" ::: "memory");   // next step's 6 loads landed
    asm volatile("s_barrier" ::: "memory");
  }
#undef MM
}

// ---------- kernel 1: split t/v/a into bf16 hi/lo + per-batch transposed hi ----------
__global__ __launch_bounds__(256) void split_x_kernel(
    const float* __restrict__ v, const float* __restrict__ t, const float* __restrict__ a,
    ushort_t* __restrict__ xhi, ushort_t* __restrict__ xlo, ushort_t* __restrict__ xT) {
  __shared__ ushort_t tile[64][65];
  int mod = blockIdx.z;
  const float* src = (mod == 0) ? v : (mod == 1 ? t : a);
  int b = blockIdx.y;
  int s0 = (blockIdx.x >> 4) * 64;
  int f0 = (blockIdx.x & 15) * 64;
  int tid = threadIdx.x;
  ushort_t* xh = xhi + mod * NX;
  ushort_t* xl = xlo + mod * NX;
  ushort_t* xt = xT + mod * NX;
  int fl = (tid & 15) * 4;
#pragma unroll
  for (int r = 0; r < 4; ++r) {
    int sl = (tid >> 4) + r * 16;
    size_t gidx = ((size_t)(b * S + s0 + sl)) * F + f0 + fl;
    float4 x = *(const float4*)(src + gidx);
    ushort_t h0 = f2bf(x.x), h1 = f2bf(x.y), h2 = f2bf(x.z), h3 = f2bf(x.w);
    *(ushort4*)(xh + gidx) = make_ushort4(h0, h1, h2, h3);
    *(ushort4*)(xl + gidx) = make_ushort4(
        f2bf(x.x - bf2f(h0)), f2bf(x.y - bf2f(h1)),
        f2bf(x.z - bf2f(h2)), f2bf(x.w - bf2f(h3)));
    tile[sl][fl] = h0; tile[sl][fl + 1] = h1; tile[sl][fl + 2] = h2; tile[sl][fl + 3] = h3;
  }
  __syncthreads();
#pragma unroll
  for (int r = 0; r < 4; ++r) {
    int flr = (tid >> 4) + r * 16;
    int sl4 = (tid & 15) * 4;
    ushort4 o = make_ushort4(tile[sl4][flr], tile[sl4 + 1][flr],
                             tile[sl4 + 2][flr], tile[sl4 + 3][flr]);
    size_t tidx = ((size_t)(b * F + f0 + flr)) * S + s0 + sl4;
    *(ushort4*)(xt + tidx) = o;
  }
}

// ---------- kernel 2: W (2048x1024) -> WT hi/lo (1024x2048) ----------
__global__ __launch_bounds__(256) void split_w_kernel(
    const float* __restrict__ w0, const float* __restrict__ w1, const float* __restrict__ w2,
    ushort_t* __restrict__ wthi, ushort_t* __restrict__ wtlo) {
  __shared__ ushort_t th[64][65];
  __shared__ ushort_t tl[64][65];
  int br = blockIdx.z;
  const float* w = (br == 0) ? w0 : (br == 1 ? w1 : w2);
  int g0 = blockIdx.x * 64;
  int f0 = blockIdx.y * 64;
  int tid = threadIdx.x;
  int gl = (tid & 15) * 4;
#pragma unroll
  for (int r = 0; r < 4; ++r) {
    int fl = (tid >> 4) + r * 16;
    float4 x = *(const float4*)(w + (size_t)(f0 + fl) * F + g0 + gl);
    ushort_t h0 = f2bf(x.x), h1 = f2bf(x.y), h2 = f2bf(x.z), h3 = f2bf(x.w);
    th[fl][gl] = h0; th[fl][gl + 1] = h1; th[fl][gl + 2] = h2; th[fl][gl + 3] = h3;
    tl[fl][gl] = f2bf(x.x - bf2f(h0));
    tl[fl][gl + 1] = f2bf(x.y - bf2f(h1));
    tl[fl][gl + 2] = f2bf(x.z - bf2f(h2));
    tl[fl][gl + 3] = f2bf(x.w - bf2f(h3));
  }
  __syncthreads();
  ushort_t* oh = wthi + br * NW;
  ushort_t* ol = wtlo + br * NW;
#pragma unroll
  for (int r = 0; r < 4; ++r) {
    int glr = (tid >> 4) + r * 16;
    int fl4 = (tid & 15) * 4;
    size_t o = (size_t)(g0 + glr) * (2 * F) + f0 + fl4;
    *(ushort4*)(oh + o) = make_ushort4(th[fl4][glr], th[fl4 + 1][glr],
                                       th[fl4 + 2][glr], th[fl4 + 3][glr]);
    *(ushort4*)(ol + o) = make_ushort4(tl[fl4][glr], tl[fl4 + 1][glr],
                                       tl[fl4 + 2][glr], tl[fl4 + 3][glr]);
  }
}

// ---------- kernel 3: Feat = tanh(concat(x1,x2) @ W + b), 8-phase split GEMM ----------
__global__ __launch_bounds__(512, 2) void feat_gemm8p_kernel(
    const ushort_t* __restrict__ xhi, const ushort_t* __restrict__ xlo,
    const ushort_t* __restrict__ wthi, const ushort_t* __restrict__ wtlo,
    const float* __restrict__ b0, const float* __restrict__ b1, const float* __restrict__ b2,
    ushort_t* __restrict__ fhi, ushort_t* __restrict__ flo) {
  constexpr int M1[3] = {1, 1, 2};   // t, t, a
  constexpr int M2[3] = {0, 2, 0};   // v, a, v
  __shared__ __attribute__((aligned(16))) ushort_t lds[3 * 24576];   // 144 KB
  int br = blockIdx.z;
  int lin = blockIdx.y * 32 + blockIdx.x;
  int gm0 = (lin >> 3) * 256;        // n-major: each XCD keeps one B-panel L2-resident
  int gn0 = (lin & 7) * 128;
  int tid = threadIdx.x, lane = tid & 63, w = tid >> 6;
  const ushort_t* a1h = xhi + M1[br] * NX + (size_t)gm0 * F;
  const ushort_t* a1l = xlo + M1[br] * NX + (size_t)gm0 * F;
  const ushort_t* a2h = xhi + M2[br] * NX + (size_t)gm0 * F;
  const ushort_t* a2l = xlo + M2[br] * NX + (size_t)gm0 * F;
  const ushort_t* bh = wthi + br * NW + (size_t)gn0 * (2 * F);
  const ushort_t* bl = wtlo + br * NW + (size_t)gn0 * (2 * F);
  f32x4 acc[4][4] = {};
  gemm8p_core<64, 1024>(a1h, a1l, a2h, a2l, F, bh, bl, 2 * F, lds, tid, acc);
  const float* bias = (br == 0) ? b0 : (br == 1 ? b1 : b2);
  ushort_t* oh = fhi + br * NX;
  ushort_t* ol = flo + br * NX;
  int wr = (w >> 1) * 64, wc = (w & 1) * 64;
#pragma unroll
  for (int i = 0; i < 4; ++i)
#pragma unroll
    for (int j = 0; j < 4; ++j)
#pragma unroll
      for (int r = 0; r < 4; ++r) {
        int row = gm0 + wr + i * 16 + (lane >> 4) * 4 + r;
        int col = gn0 + wc + j * 16 + (lane & 15);
        float val = tanhf(acc[i][j][r] + bias[col]);
        ushort_t h = f2bf(val);
        size_t o = (size_t)row * F + col;
        oh[o] = h;
        ol[o] = f2bf(val - bf2f(h));
      }
}

// ---------- kernel 4: scores = q @ feat^T, 8-phase split GEMM, fp32 out ----------
__global__ __launch_bounds__(512, 2) void scores_gemm8p_kernel(
    const ushort_t* __restrict__ xhi, const ushort_t* __restrict__ xlo,
    const ushort_t* __restrict__ fhi, const ushort_t* __restrict__ flo,
    float* __restrict__ scores) {
  constexpr int QM[3] = {2, 0, 1};   // a, v, t
  __shared__ __attribute__((aligned(16))) ushort_t lds[3 * 24576];   // 144 KB
  int z = blockIdx.z;
  int br = z >> 4, b = z & 15;
  int gm0 = blockIdx.x * 256;
  int gn0 = blockIdx.y * 128;
  int tid = threadIdx.x, lane = tid & 63, w = tid >> 6;
  const ushort_t* qh = xhi + QM[br] * NX + (size_t)(b * S + gm0) * F;
  const ushort_t* ql = xlo + QM[br] * NX + (size_t)(b * S + gm0) * F;
  const ushort_t* kh = fhi + br * NX + (size_t)(b * S + gn0) * F;
  const ushort_t* kl = flo + br * NX + (size_t)(b * S + gn0) * F;
  f32x4 acc[4][4] = {};
  gemm8p_core<32, 2048>(qh, ql, qh, ql, F, kh, kl, F, lds, tid, acc);
  float* out = scores + (size_t)z * S * S;
  int wr = (w >> 1) * 64, wc = (w & 1) * 64;
#pragma unroll
  for (int i = 0; i < 4; ++i)
#pragma unroll
    for (int j = 0; j < 4; ++j)
#pragma unroll
      for (int r = 0; r < 4; ++r) {
        int row = gm0 + wr + i * 16 + (lane >> 4) * 4 + r;
        int col = gn0 + wc + j * 16 + (lane & 15);
        out[(size_t)row * S + col] = acc[i][j][r];
      }
}

// ---------- kernel 5: row softmax (512), fp32 in -> bf16 p ----------
__global__ __launch_bounds__(256) void softmax_kernel(
    const float* __restrict__ scores, ushort_t* __restrict__ p) {
  int wave = threadIdx.x >> 6, lane = threadIdx.x & 63;
  int row = blockIdx.x * 4 + wave;
  const float* src = scores + (size_t)row * S;
  float4 v0 = *(const float4*)(src + lane * 8);
  float4 v1 = *(const float4*)(src + lane * 8 + 4);
  float m = fmaxf(fmaxf(fmaxf(v0.x, v0.y), fmaxf(v0.z, v0.w)),
                  fmaxf(fmaxf(v1.x, v1.y), fmaxf(v1.z, v1.w)));
#pragma unroll
  for (int d = 1; d < 64; d <<= 1) m = fmaxf(m, __shfl_xor(m, d));
  float e[8] = {expf(v0.x - m), expf(v0.y - m), expf(v0.z - m), expf(v0.w - m),
                expf(v1.x - m), expf(v1.y - m), expf(v1.z - m), expf(v1.w - m)};
  float s = ((e[0] + e[1]) + (e[2] + e[3])) + ((e[4] + e[5]) + (e[6] + e[7]));
#pragma unroll
  for (int d = 1; d < 64; d <<= 1) s += __shfl_xor(s, d);
  float inv = 1.0f / s;
  u16x8 o;
#pragma unroll
  for (int j = 0; j < 8; ++j) o[j] = f2bf(e[j] * inv);
  *(u16x8*)(p + (size_t)row * S + lane * 8) = o;
}

// ---------- kernel 6: O = (p @ q) * feat, plain bf16 MFMA, fp32 out ----------
__global__ __launch_bounds__(256) void pv_gemm_kernel(
    const ushort_t* __restrict__ p, const ushort_t* __restrict__ xT,
    const ushort_t* __restrict__ fhi, const ushort_t* __restrict__ flo,
    float* __restrict__ out) {
  constexpr int QM[3] = {2, 0, 1};
  __shared__ __attribute__((aligned(16))) ushort_t lds[2 * 4096];
  ushort_t* Ah = lds;
  ushort_t* Bh = lds + 4096;
  int z = blockIdx.z;
  int br = z >> 4, b = z & 15;
  int gm0 = blockIdx.x * 128;
  int gn0 = blockIdx.y * 128;
  int tid = threadIdx.x, lane = tid & 63, wave = tid >> 6;
  int wr = (wave >> 1) * 64, wc = (wave & 1) * 64;
  const ushort_t* pa = p + (size_t)z * S * S;
  const ushort_t* qt = xT + QM[br] * NX + (size_t)b * F * S;   // [f][s]
  f32x4 acc[4][4] = {};
  for (int k0 = 0; k0 < S; k0 += 32) {
    stage_tile(Ah, pa + (size_t)gm0 * S + k0, S, tid);
    stage_tile(Bh, qt + (size_t)gn0 * S + k0, S, tid);
    __syncthreads();
    b16x8 af[4], bf_[4];
#pragma unroll
    for (int i = 0; i < 4; ++i) {
      af[i] = frag_ld(Ah, wr + i * 16, lane);
      bf_[i] = frag_ld(Bh, wc + i * 16, lane);
    }
#pragma unroll
    for (int i = 0; i < 4; ++i)
#pragma unroll
      for (int j = 0; j < 4; ++j)
        acc[i][j] = mfma16(af[i], bf_[j], acc[i][j]);
    __syncthreads();
  }
  const ushort_t* eh = fhi + br * NX + (size_t)(b * S) * F;
  const ushort_t* el = flo + br * NX + (size_t)(b * S) * F;
#pragma unroll
  for (int i = 0; i < 4; ++i)
#pragma unroll
    for (int j = 0; j < 4; ++j)
#pragma unroll
      for (int r = 0; r < 4; ++r) {
        int row = gm0 + wr + i * 16 + (lane >> 4) * 4 + r;
        int col = gn0 + wc + j * 16 + (lane & 15);
        size_t fo = (size_t)row * F + col;
        float fe = bf2f(eh[fo]) + bf2f(el[fo]);
        out[(size_t)(b * S + row) * (3 * F) + br * F + col] = acc[i][j][r] * fe;
      }
}

extern "C" void kernel_launch(void* const* d_in, const int* in_sizes, int n_in,
                              void* d_out, int out_size, void* d_ws, size_t ws_size,
                              hipStream_t stream) {
  (void)in_sizes; (void)n_in; (void)out_size; (void)ws_size;
  const float* v = (const float*)d_in[0];
  const float* t = (const float*)d_in[1];
  const float* a = (const float*)d_in[2];
  const float* W_tv = (const float*)d_in[3];
  const float* b_tv = (const float*)d_in[4];
  const float* W_ta = (const float*)d_in[5];
  const float* b_ta = (const float*)d_in[6];
  const float* W_av = (const float*)d_in[7];
  const float* b_av = (const float*)d_in[8];
  float* out = (float*)d_out;

  ushort_t* xhi = (ushort_t*)d_ws;
  ushort_t* xlo = xhi + 3 * NX;
  ushort_t* xT = xlo + 3 * NX;
  ushort_t* wthi = xT + 3 * NX;
  ushort_t* wtlo = wthi + 3 * NW;
  ushort_t* fhi = wtlo + 3 * NW;
  ushort_t* flo = fhi + 3 * NX;
  float* scores = (float*)(flo + 3 * NX);
  ushort_t* pbuf = (ushort_t*)(scores + NSC);

  split_x_kernel<<<dim3(128, 16, 3), 256, 0, stream>>>(v, t, a, xhi, xlo, xT);
  split_w_kernel<<<dim3(16, 32, 3), 256, 0, stream>>>(W_tv, W_ta, W_av, wthi, wtlo);
  feat_gemm8p_kernel<<<dim3(32, 8, 3), 512, 0, stream>>>(xhi, xlo, wthi, wtlo,
                                                         b_tv, b_ta, b_av, fhi, flo);
  scores_gemm8p_kernel<<<dim3(2, 4, 48), 512, 0, stream>>>(xhi, xlo, fhi, flo, scores);
  softmax_kernel<<<dim3((3 * B * S) / 4), 256, 0, stream>>>(scores, pbuf);
  pv_gemm_kernel<<<dim3(4, 8, 48), 256, 0, stream>>>(pbuf, xT, fhi, flo, out);
}

// Round 3
// 520.387 us; speedup vs baseline: 1.1508x; 1.1508x over previous
//
#include <hip/hip_runtime.h>

typedef unsigned short ushort_t;
typedef __bf16 b16x8 __attribute__((ext_vector_type(8)));
typedef float f32x4 __attribute__((ext_vector_type(4)));
typedef unsigned short u16x8 __attribute__((ext_vector_type(8)));

#define DEVINL __device__ __forceinline__

constexpr int B = 16, S = 512, F = 1024;
constexpr int M_ROWS = B * S;                    // 8192
constexpr size_t NX = (size_t)M_ROWS * F;        // 8,388,608 elems per modality
constexpr size_t NW = (size_t)F * (2 * F);       // 2,097,152 elems per branch
constexpr size_t NSC = (size_t)3 * B * S * S;    // 12,582,912 score elems

// packed pitches (elements): per row, chunk c holds 32 hi at c*64, 32 lo at c*64+32
constexpr int XP = 2 * F;        // 2048 : x / q / feat rows (K=1024)
constexpr int WP = 4 * F;        // 4096 : WT rows (K=2048)

// ---------- bf16 helpers (RNE) ----------
DEVINL ushort_t f2bf(float f) {
  unsigned int u = __builtin_bit_cast(unsigned int, f);
  u += 0x7FFFu + ((u >> 16) & 1u);
  return (ushort_t)(u >> 16);
}
DEVINL float bf2f(ushort_t h) {
  unsigned int u = ((unsigned int)h) << 16;
  return __builtin_bit_cast(float, u);
}
// packed index of hi element (row, k); lo at +32
DEVINL size_t pk(int row, int k, int pitch) {
  return (size_t)row * pitch + ((k >> 5) * 64) + (k & 31);
}

// ---------- async global->LDS (16B per lane) ----------
DEVINL void gload_lds16(const void* g, void* l) {
  __builtin_amdgcn_global_load_lds(
      (__attribute__((address_space(1))) void*)(g),
      (__attribute__((address_space(3))) void*)(l), 16, 0, 0);
}

DEVINL f32x4 mfma16(b16x8 a, b16x8 b, f32x4 c) {
  return __builtin_amdgcn_mfma_f32_16x16x32_bf16(a, b, c, 0, 0, 0);
}

// ---------- 2-phase helpers (used by pv_gemm only) ----------
DEVINL void stage_tile(ushort_t* lds, const ushort_t* src, int ld, int tid) {
  int wave = tid >> 6;
#pragma unroll
  for (int it = 0; it < 2; ++it) {
    int c = it * 256 + tid;
    const ushort_t* g = src + (size_t)(c >> 2) * ld + (c & 3) * 8;
    ushort_t* l = lds + (size_t)(it * 256 + wave * 64) * 8;
    gload_lds16(g, l);
  }
}
DEVINL b16x8 frag_ld(const ushort_t* lds, int rb, int lane) {
  return *(const b16x8*)(lds + (size_t)(rb + (lane & 15)) * 32 + (lane >> 4) * 8);
}

// ================== 2-phase-per-step split-bf16 GEMM core ==================
// C[256x128] = (Ah+Al)*(Bh+Bl)^T, 3-MFMA Ootomo (hh+hl+lh), packed hi|lo source.
// 8 waves (4M x 2N), wave-tile 64x64 = 4x4 frags of 16x16x32, BK=32.
// LDS: 3 buffers x {Ah[256][32],Al,Bh[128][32],Bl} = 3 x 48KB.
// 6 loads/wave/step, depth-2 prefetch, counted vmcnt(6) once per step.
template <int KSTEPS, int SPLIT_STEP>
DEVINL void gemm8p_core(const ushort_t* __restrict__ a1, const ushort_t* __restrict__ a2, int lda,
                        const ushort_t* __restrict__ bsrc, int ldb,
                        ushort_t* lds, int tid, f32x4 (&acc)[4][4]) {
  constexpr int BUFE = 24576, ALO = 8192, BHI = 16384, BLO = 20480;
  const int lane = tid & 63, w = tid >> 6;
  const int wr = (w >> 1) * 64, wc = (w & 1) * 64;
  // staging: lane -> row (l>>2), 16B slot (l&3) XOR-swizzled by (row>>1)&3
  const int scol = (((lane & 3) ^ ((lane >> 3) & 3)) * 8);
  const size_t arow = (size_t)(w * 32 + (lane >> 2));
  const size_t brow = (size_t)(w * 16 + (lane >> 2));
  // ds_read: row rb+(lane&15), logical slot lane>>4 -> phys slot ^((row>>1)&3)
  const int foff = (lane & 15) * 32 + (((lane >> 4) ^ ((lane >> 1) & 3)) * 8);

  auto stA = [&](int sb, int ks) {
    const ushort_t* base = (ks < SPLIT_STEP) ? a1 : a2;
    int kk = (ks < SPLIT_STEP) ? ks : ks - SPLIT_STEP;
    const ushort_t* s = base + arow * lda + kk * 64 + scol;
    ushort_t* dh = lds + sb * BUFE + w * 1024;
    ushort_t* dl = lds + sb * BUFE + ALO + w * 1024;
    gload_lds16(s, dh);
    gload_lds16(s + (size_t)16 * lda, dh + 512);
    gload_lds16(s + 32, dl);                          // same 128B line as hi
    gload_lds16(s + 32 + (size_t)16 * lda, dl + 512);
  };
  auto stB = [&](int sb, int ks) {
    const ushort_t* s = bsrc + brow * ldb + ks * 64 + scol;
    gload_lds16(s, lds + sb * BUFE + BHI + w * 512);
    gload_lds16(s + 32, lds + sb * BUFE + BLO + w * 512);
  };
  auto FR = [&](const ushort_t* rgn, int rb) -> b16x8 {
    return *(const b16x8*)(rgn + rb * 32 + foff);
  };

  // prologue: stage steps 0 and 1
  stA(0, 0); stB(0, 0);
  stA(1, 1); stB(1, 1);
  asm volatile("s_waitcnt vmcnt(6)" ::: "memory");   // step 0 landed
  asm volatile("s_barrier" ::: "memory");

  for (int t = 0; t < KSTEPS; ++t) {
    const int cb = t % 3, sb = (t + 2) % 3;
    const int ks = (t + 2) & (KSTEPS - 1);           // clamped tail keeps vmcnt uniform
    const ushort_t* L = lds + cb * BUFE;
    b16x8 rAh[4], rAl[4], rBh[4], rBl[4];
    // ---- phase A: all A frags + B[0..1]; MFMA m0123 x n01 (24)
#pragma unroll
    for (int i = 0; i < 4; ++i) {
      rAh[i] = FR(L, wr + i * 16);
      rAl[i] = FR(L + ALO, wr + i * 16);
    }
    rBh[0] = FR(L + BHI, wc);      rBh[1] = FR(L + BHI, wc + 16);
    rBl[0] = FR(L + BLO, wc);      rBl[1] = FR(L + BLO, wc + 16);
    stA(sb, ks);
    asm volatile("s_barrier" ::: "memory");
    asm volatile("s_waitcnt lgkmcnt(0)" ::: "memory");
    __builtin_amdgcn_s_setprio(1);
#pragma unroll
    for (int j = 0; j < 2; ++j)
#pragma unroll
      for (int i = 0; i < 4; ++i) acc[i][j] = mfma16(rAh[i], rBh[j], acc[i][j]);
#pragma unroll
    for (int j = 0; j < 2; ++j)
#pragma unroll
      for (int i = 0; i < 4; ++i) acc[i][j] = mfma16(rAh[i], rBl[j], acc[i][j]);
#pragma unroll
    for (int j = 0; j < 2; ++j)
#pragma unroll
      for (int i = 0; i < 4; ++i) acc[i][j] = mfma16(rAl[i], rBh[j], acc[i][j]);
    __builtin_amdgcn_s_setprio(0);
    asm volatile("s_barrier" ::: "memory");
    // ---- phase B: B[2..3]; MFMA m0123 x n23 (24); counted vmcnt at step end
    rBh[2] = FR(L + BHI, wc + 32); rBh[3] = FR(L + BHI, wc + 48);
    rBl[2] = FR(L + BLO, wc + 32); rBl[3] = FR(L + BLO, wc + 48);
    stB(sb, ks);
    asm volatile("s_barrier" ::: "memory");
    asm volatile("s_waitcnt lgkmcnt(0)" ::: "memory");
    __builtin_amdgcn_s_setprio(1);
#pragma unroll
    for (int j = 2; j < 4; ++j)
#pragma unroll
      for (int i = 0; i < 4; ++i) acc[i][j] = mfma16(rAh[i], rBh[j], acc[i][j]);
#pragma unroll
    for (int j = 2; j < 4; ++j)
#pragma unroll
      for (int i = 0; i < 4; ++i) acc[i][j] = mfma16(rAh[i], rBl[j], acc[i][j]);
#pragma unroll
    for (int j = 2; j < 4; ++j)
#pragma unroll
      for (int i = 0; i < 4; ++i) acc[i][j] = mfma16(rAl[i], rBh[j], acc[i][j]);
    __builtin_amdgcn_s_setprio(0);
    asm volatile("s_waitcnt vmcnt(6)" ::: "memory"); // next step's loads landed
    asm volatile("s_barrier" ::: "memory");
  }
}

// ---------- kernel 1: split t/v/a -> packed hi|lo + transposed hi ----------
__global__ __launch_bounds__(256) void split_x_kernel(
    const float* __restrict__ v, const float* __restrict__ t, const float* __restrict__ a,
    ushort_t* __restrict__ xpack, ushort_t* __restrict__ xT) {
  __shared__ ushort_t tile[64][65];
  int mod = blockIdx.z;
  const float* src = (mod == 0) ? v : (mod == 1 ? t : a);
  int b = blockIdx.y;
  int s0 = (blockIdx.x >> 4) * 64;
  int f0 = (blockIdx.x & 15) * 64;
  int tid = threadIdx.x;
  ushort_t* xp = xpack + mod * (NX * 2);
  ushort_t* xt = xT + mod * NX;
  int fl = (tid & 15) * 4;
#pragma unroll
  for (int r = 0; r < 4; ++r) {
    int sl = (tid >> 4) + r * 16;
    int row = b * S + s0 + sl;
    float4 x = *(const float4*)(src + (size_t)row * F + f0 + fl);
    ushort_t h0 = f2bf(x.x), h1 = f2bf(x.y), h2 = f2bf(x.z), h3 = f2bf(x.w);
    size_t o = pk(row, f0 + fl, XP);
    *(ushort4*)(xp + o) = make_ushort4(h0, h1, h2, h3);
    *(ushort4*)(xp + o + 32) = make_ushort4(
        f2bf(x.x - bf2f(h0)), f2bf(x.y - bf2f(h1)),
        f2bf(x.z - bf2f(h2)), f2bf(x.w - bf2f(h3)));
    tile[sl][fl] = h0; tile[sl][fl + 1] = h1; tile[sl][fl + 2] = h2; tile[sl][fl + 3] = h3;
  }
  __syncthreads();
#pragma unroll
  for (int r = 0; r < 4; ++r) {
    int flr = (tid >> 4) + r * 16;
    int sl4 = (tid & 15) * 4;
    ushort4 o = make_ushort4(tile[sl4][flr], tile[sl4 + 1][flr],
                             tile[sl4 + 2][flr], tile[sl4 + 3][flr]);
    size_t tidx = ((size_t)(b * F + f0 + flr)) * S + s0 + sl4;
    *(ushort4*)(xt + tidx) = o;
  }
}

// ---------- kernel 2: W (2048x1024) -> WT packed hi|lo (1024 rows x K=2048) ----------
__global__ __launch_bounds__(256) void split_w_kernel(
    const float* __restrict__ w0, const float* __restrict__ w1, const float* __restrict__ w2,
    ushort_t* __restrict__ wtpack) {
  __shared__ ushort_t th[64][65];
  __shared__ ushort_t tl[64][65];
  int br = blockIdx.z;
  const float* w = (br == 0) ? w0 : (br == 1 ? w1 : w2);
  int g0 = blockIdx.x * 64;   // cols of W (rows of WT)
  int f0 = blockIdx.y * 64;   // rows of W (K dim)
  int tid = threadIdx.x;
  int gl = (tid & 15) * 4;
#pragma unroll
  for (int r = 0; r < 4; ++r) {
    int fl = (tid >> 4) + r * 16;
    float4 x = *(const float4*)(w + (size_t)(f0 + fl) * F + g0 + gl);
    ushort_t h0 = f2bf(x.x), h1 = f2bf(x.y), h2 = f2bf(x.z), h3 = f2bf(x.w);
    th[fl][gl] = h0; th[fl][gl + 1] = h1; th[fl][gl + 2] = h2; th[fl][gl + 3] = h3;
    tl[fl][gl] = f2bf(x.x - bf2f(h0));
    tl[fl][gl + 1] = f2bf(x.y - bf2f(h1));
    tl[fl][gl + 2] = f2bf(x.z - bf2f(h2));
    tl[fl][gl + 3] = f2bf(x.w - bf2f(h3));
  }
  __syncthreads();
  ushort_t* op = wtpack + br * (NW * 2);
#pragma unroll
  for (int r = 0; r < 4; ++r) {
    int glr = (tid >> 4) + r * 16;
    int fl4 = (tid & 15) * 4;
    size_t o = pk(g0 + glr, f0 + fl4, WP);
    *(ushort4*)(op + o) = make_ushort4(th[fl4][glr], th[fl4 + 1][glr],
                                       th[fl4 + 2][glr], th[fl4 + 3][glr]);
    *(ushort4*)(op + o + 32) = make_ushort4(tl[fl4][glr], tl[fl4 + 1][glr],
                                            tl[fl4 + 2][glr], tl[fl4 + 3][glr]);
  }
}

// ---------- kernel 3: Feat = tanh(concat(x1,x2) @ W + b) ----------
__global__ __launch_bounds__(512, 2) void feat_gemm8p_kernel(
    const ushort_t* __restrict__ xpack, const ushort_t* __restrict__ wtpack,
    const float* __restrict__ b0, const float* __restrict__ b1, const float* __restrict__ b2,
    ushort_t* __restrict__ fpack) {
  constexpr int M1[3] = {1, 1, 2};   // t, t, a
  constexpr int M2[3] = {0, 2, 0};   // v, a, v
  __shared__ __attribute__((aligned(16))) ushort_t lds[3 * 24576];   // 144 KB
  int br = blockIdx.z;
  int lin = blockIdx.x;
  // XCD-chunked: lin&7 = XCD (round-robin dispatch); 8 n-blocks sharing an
  // A-panel land on the SAME XCD -> A fetched once per panel into that L2.
  int gm0 = ((lin & 7) * 4 + (lin >> 6)) * 256;
  int gn0 = ((lin >> 3) & 7) * 128;
  int tid = threadIdx.x, lane = tid & 63, w = tid >> 6;
  const ushort_t* a1 = xpack + M1[br] * (NX * 2) + (size_t)gm0 * XP;
  const ushort_t* a2 = xpack + M2[br] * (NX * 2) + (size_t)gm0 * XP;
  const ushort_t* bb = wtpack + br * (NW * 2) + (size_t)gn0 * WP;
  f32x4 acc[4][4] = {};
  gemm8p_core<64, 32>(a1, a2, XP, bb, WP, lds, tid, acc);
  const float* bias = (br == 0) ? b0 : (br == 1 ? b1 : b2);
  ushort_t* op = fpack + br * (NX * 2);
  int wr = (w >> 1) * 64, wc = (w & 1) * 64;
#pragma unroll
  for (int i = 0; i < 4; ++i)
#pragma unroll
    for (int j = 0; j < 4; ++j)
#pragma unroll
      for (int r = 0; r < 4; ++r) {
        int row = gm0 + wr + i * 16 + (lane >> 4) * 4 + r;
        int col = gn0 + wc + j * 16 + (lane & 15);
        float val = tanhf(acc[i][j][r] + bias[col]);
        ushort_t h = f2bf(val);
        size_t o = pk(row, col, XP);
        op[o] = h;
        op[o + 32] = f2bf(val - bf2f(h));
      }
}

// ---------- kernel 4: scores = q @ feat^T, fp32 out ----------
__global__ __launch_bounds__(512, 2) void scores_gemm8p_kernel(
    const ushort_t* __restrict__ xpack, const ushort_t* __restrict__ fpack,
    float* __restrict__ scores) {
  constexpr int QM[3] = {2, 0, 1};   // a, v, t
  __shared__ __attribute__((aligned(16))) ushort_t lds[3 * 24576];
  int z = blockIdx.z;
  int br = z >> 4, b = z & 15;
  int gm0 = blockIdx.x * 256;
  int gn0 = blockIdx.y * 128;
  int tid = threadIdx.x, lane = tid & 63, w = tid >> 6;
  const ushort_t* a1 = xpack + QM[br] * (NX * 2) + (size_t)(b * S + gm0) * XP;
  const ushort_t* bb = fpack + br * (NX * 2) + (size_t)(b * S + gn0) * XP;
  f32x4 acc[4][4] = {};
  gemm8p_core<32, 32>(a1, a1, XP, bb, XP, lds, tid, acc);   // SPLIT_STEP=KSTEPS: a2 unused
  float* out = scores + (size_t)z * S * S;
  int wr = (w >> 1) * 64, wc = (w & 1) * 64;
#pragma unroll
  for (int i = 0; i < 4; ++i)
#pragma unroll
    for (int j = 0; j < 4; ++j)
#pragma unroll
      for (int r = 0; r < 4; ++r) {
        int row = gm0 + wr + i * 16 + (lane >> 4) * 4 + r;
        int col = gn0 + wc + j * 16 + (lane & 15);
        out[(size_t)row * S + col] = acc[i][j][r];
      }
}

// ---------- kernel 5: row softmax (512), fp32 in -> bf16 p ----------
__global__ __launch_bounds__(256) void softmax_kernel(
    const float* __restrict__ scores, ushort_t* __restrict__ p) {
  int wave = threadIdx.x >> 6, lane = threadIdx.x & 63;
  int row = blockIdx.x * 4 + wave;
  const float* src = scores + (size_t)row * S;
  float4 v0 = *(const float4*)(src + lane * 8);
  float4 v1 = *(const float4*)(src + lane * 8 + 4);
  float m = fmaxf(fmaxf(fmaxf(v0.x, v0.y), fmaxf(v0.z, v0.w)),
                  fmaxf(fmaxf(v1.x, v1.y), fmaxf(v1.z, v1.w)));
#pragma unroll
  for (int d = 1; d < 64; d <<= 1) m = fmaxf(m, __shfl_xor(m, d));
  float e[8] = {expf(v0.x - m), expf(v0.y - m), expf(v0.z - m), expf(v0.w - m),
                expf(v1.x - m), expf(v1.y - m), expf(v1.z - m), expf(v1.w - m)};
  float s = ((e[0] + e[1]) + (e[2] + e[3])) + ((e[4] + e[5]) + (e[6] + e[7]));
#pragma unroll
  for (int d = 1; d < 64; d <<= 1) s += __shfl_xor(s, d);
  float inv = 1.0f / s;
  u16x8 o;
#pragma unroll
  for (int j = 0; j < 8; ++j) o[j] = f2bf(e[j] * inv);
  *(u16x8*)(p + (size_t)row * S + lane * 8) = o;
}

// ---------- kernel 6: O = (p @ q) * feat, plain bf16 MFMA, fp32 out ----------
__global__ __launch_bounds__(256) void pv_gemm_kernel(
    const ushort_t* __restrict__ p, const ushort_t* __restrict__ xT,
    const ushort_t* __restrict__ fpack, float* __restrict__ out) {
  constexpr int QM[3] = {2, 0, 1};
  __shared__ __attribute__((aligned(16))) ushort_t lds[2 * 4096];
  ushort_t* Ah = lds;
  ushort_t* Bh = lds + 4096;
  int z = blockIdx.z;
  int br = z >> 4, b = z & 15;
  int gm0 = blockIdx.x * 128;
  int gn0 = blockIdx.y * 128;
  int tid = threadIdx.x, lane = tid & 63, wave = tid >> 6;
  int wr = (wave >> 1) * 64, wc = (wave & 1) * 64;
  const ushort_t* pa = p + (size_t)z * S * S;
  const ushort_t* qt = xT + QM[br] * NX + (size_t)b * F * S;   // [f][s]
  f32x4 acc[4][4] = {};
  for (int k0 = 0; k0 < S; k0 += 32) {
    stage_tile(Ah, pa + (size_t)gm0 * S + k0, S, tid);
    stage_tile(Bh, qt + (size_t)gn0 * S + k0, S, tid);
    __syncthreads();
    b16x8 af[4], bf_[4];
#pragma unroll
    for (int i = 0; i < 4; ++i) {
      af[i] = frag_ld(Ah, wr + i * 16, lane);
      bf_[i] = frag_ld(Bh, wc + i * 16, lane);
    }
#pragma unroll
    for (int i = 0; i < 4; ++i)
#pragma unroll
      for (int j = 0; j < 4; ++j)
        acc[i][j] = mfma16(af[i], bf_[j], acc[i][j]);
    __syncthreads();
  }
  const ushort_t* fp = fpack + br * (NX * 2);
#pragma unroll
  for (int i = 0; i < 4; ++i)
#pragma unroll
    for (int j = 0; j < 4; ++j)
#pragma unroll
      for (int r = 0; r < 4; ++r) {
        int row = gm0 + wr + i * 16 + (lane >> 4) * 4 + r;
        int col = gn0 + wc + j * 16 + (lane & 15);
        size_t fo = pk(b * S + row, col, XP);
        float fe = bf2f(fp[fo]) + bf2f(fp[fo + 32]);
        out[(size_t)(b * S + row) * (3 * F) + br * F + col] = acc[i][j][r] * fe;
      }
}

extern "C" void kernel_launch(void* const* d_in, const int* in_sizes, int n_in,
                              void* d_out, int out_size, void* d_ws, size_t ws_size,
                              hipStream_t stream) {
  (void)in_sizes; (void)n_in; (void)out_size; (void)ws_size;
  const float* v = (const float*)d_in[0];
  const float* t = (const float*)d_in[1];
  const float* a = (const float*)d_in[2];
  const float* W_tv = (const float*)d_in[3];
  const float* b_tv = (const float*)d_in[4];
  const float* W_ta = (const float*)d_in[5];
  const float* b_ta = (const float*)d_in[6];
  const float* W_av = (const float*)d_in[7];
  const float* b_av = (const float*)d_in[8];
  float* out = (float*)d_out;

  // ws layout (~352 MB total, same as R2)
  ushort_t* xpack = (ushort_t*)d_ws;            // 3 * NX*2
  ushort_t* xT = xpack + 3 * (NX * 2);          // 3 * NX
  ushort_t* wtpack = xT + 3 * NX;               // 3 * NW*2
  ushort_t* fpack = wtpack + 3 * (NW * 2);      // 3 * NX*2
  float* scores = (float*)(fpack + 3 * (NX * 2));
  ushort_t* pbuf = (ushort_t*)(scores + NSC);

  split_x_kernel<<<dim3(128, 16, 3), 256, 0, stream>>>(v, t, a, xpack, xT);
  split_w_kernel<<<dim3(16, 32, 3), 256, 0, stream>>>(W_tv, W_ta, W_av, wtpack);
  feat_gemm8p_kernel<<<dim3(256, 1, 3), 512, 0, stream>>>(xpack, wtpack,
                                                          b_tv, b_ta, b_av, fpack);
  scores_gemm8p_kernel<<<dim3(2, 4, 48), 512, 0, stream>>>(xpack, fpack, scores);
  softmax_kernel<<<dim3((3 * B * S) / 4), 256, 0, stream>>>(scores, pbuf);
  pv_gemm_kernel<<<dim3(4, 8, 48), 256, 0, stream>>>(pbuf, xT, fpack, out);
}

// Round 4
// 513.022 us; speedup vs baseline: 1.1673x; 1.0144x over previous
//
#include <hip/hip_runtime.h>

typedef unsigned short ushort_t;
typedef __bf16 b16x8 __attribute__((ext_vector_type(8)));
typedef float f32x4 __attribute__((ext_vector_type(4)));
typedef unsigned short u16x8 __attribute__((ext_vector_type(8)));

#define DEVINL __device__ __forceinline__

constexpr int B = 16, S = 512, F = 1024;
constexpr int M_ROWS = B * S;                    // 8192
constexpr size_t NX = (size_t)M_ROWS * F;        // 8,388,608 elems per modality
constexpr size_t NW = (size_t)F * (2 * F);       // 2,097,152 elems per branch
constexpr size_t NSC = (size_t)3 * B * S * S;    // 12,582,912 score elems

// packed pitches (elements): per row, chunk c holds 32 hi at c*64, 32 lo at c*64+32
constexpr int XP = 2 * F;        // 2048 : x / q / feat rows (K=1024)
constexpr int WP = 4 * F;        // 4096 : WT rows (K=2048)

// ---------- bf16 helpers (RNE) ----------
DEVINL ushort_t f2bf(float f) {
  unsigned int u = __builtin_bit_cast(unsigned int, f);
  u += 0x7FFFu + ((u >> 16) & 1u);
  return (ushort_t)(u >> 16);
}
DEVINL float bf2f(ushort_t h) {
  unsigned int u = ((unsigned int)h) << 16;
  return __builtin_bit_cast(float, u);
}
// packed index of hi element (row, k); lo at +32
DEVINL size_t pk(int row, int k, int pitch) {
  return (size_t)row * pitch + ((k >> 5) * 64) + (k & 31);
}

// ---------- async global->LDS (16B per lane) ----------
DEVINL void gload_lds16(const void* g, void* l) {
  __builtin_amdgcn_global_load_lds(
      (__attribute__((address_space(1))) void*)(g),
      (__attribute__((address_space(3))) void*)(l), 16, 0, 0);
}

DEVINL f32x4 mfma16(b16x8 a, b16x8 b, f32x4 c) {
  return __builtin_amdgcn_mfma_f32_16x16x32_bf16(a, b, c, 0, 0, 0);
}

// ---------- 2-phase helpers (used by pv_gemm only) ----------
DEVINL void stage_tile(ushort_t* lds, const ushort_t* src, int ld, int tid) {
  int wave = tid >> 6;
#pragma unroll
  for (int it = 0; it < 2; ++it) {
    int c = it * 256 + tid;
    const ushort_t* g = src + (size_t)(c >> 2) * ld + (c & 3) * 8;
    ushort_t* l = lds + (size_t)(it * 256 + wave * 64) * 8;
    gload_lds16(g, l);
  }
}
DEVINL b16x8 frag_ld(const ushort_t* lds, int rb, int lane) {
  return *(const b16x8*)(lds + (size_t)(rb + (lane & 15)) * 32 + (lane >> 4) * 8);
}

// ================== 2-phase-per-step split-bf16 GEMM core ==================
// C[256x128] = (Ah+Al)*(Bh+Bl)^T, 3-MFMA Ootomo (hh+hl+lh), packed hi|lo source.
// 8 waves (4M x 2N), wave-tile 64x64 = 4x4 frags of 16x16x32, BK=32.
// LDS: 3 buffers x {Ah[256][32],Al,Bh[128][32],Bl} = 3 x 48KB.
// 6 loads/wave/step, depth-2 prefetch, counted vmcnt(6) once per step.
// NO lgkmcnt(0) drain: compiler emits counted per-operand lgkm waits, so
// ds_read returns drain under the MFMA stream (T4 applied to lgkm).
template <int KSTEPS, int SPLIT_STEP>
DEVINL void gemm8p_core(const ushort_t* __restrict__ a1, const ushort_t* __restrict__ a2, int lda,
                        const ushort_t* __restrict__ bsrc, int ldb,
                        ushort_t* lds, int tid, f32x4 (&acc)[4][4]) {
  constexpr int BUFE = 24576, ALO = 8192, BHI = 16384, BLO = 20480;
  const int lane = tid & 63, w = tid >> 6;
  const int wr = (w >> 1) * 64, wc = (w & 1) * 64;
  // staging: lane -> row (l>>2), 16B slot (l&3) XOR-swizzled by (row>>1)&3
  const int scol = (((lane & 3) ^ ((lane >> 3) & 3)) * 8);
  const size_t arow = (size_t)(w * 32 + (lane >> 2));
  const size_t brow = (size_t)(w * 16 + (lane >> 2));
  // ds_read: row rb+(lane&15), logical slot lane>>4 -> phys slot ^((row>>1)&3)
  const int foff = (lane & 15) * 32 + (((lane >> 4) ^ ((lane >> 1) & 3)) * 8);

  auto stA = [&](int sb, int ks) {
    const ushort_t* base = (ks < SPLIT_STEP) ? a1 : a2;
    int kk = (ks < SPLIT_STEP) ? ks : ks - SPLIT_STEP;
    const ushort_t* s = base + arow * lda + kk * 64 + scol;
    ushort_t* dh = lds + sb * BUFE + w * 1024;
    ushort_t* dl = lds + sb * BUFE + ALO + w * 1024;
    gload_lds16(s, dh);
    gload_lds16(s + (size_t)16 * lda, dh + 512);
    gload_lds16(s + 32, dl);                          // same 128B line as hi
    gload_lds16(s + 32 + (size_t)16 * lda, dl + 512);
  };
  auto stB = [&](int sb, int ks) {
    const ushort_t* s = bsrc + brow * ldb + ks * 64 + scol;
    gload_lds16(s, lds + sb * BUFE + BHI + w * 512);
    gload_lds16(s + 32, lds + sb * BUFE + BLO + w * 512);
  };
  auto FR = [&](const ushort_t* rgn, int rb) -> b16x8 {
    return *(const b16x8*)(rgn + rb * 32 + foff);
  };

  // prologue: stage steps 0 and 1
  stA(0, 0); stB(0, 0);
  stA(1, 1); stB(1, 1);
  asm volatile("s_waitcnt vmcnt(6)" ::: "memory");   // step 0 landed
  asm volatile("s_barrier" ::: "memory");

  for (int t = 0; t < KSTEPS; ++t) {
    const int cb = t % 3, sb = (t + 2) % 3;
    const int ks = (t + 2) & (KSTEPS - 1);           // clamped tail keeps vmcnt uniform
    const ushort_t* L = lds + cb * BUFE;
    b16x8 rAh[4], rAl[4], rBh[4], rBl[4];
    // ---- phase A: reads ordered to match MFMA consumption (Bh,Ah first)
    rBh[0] = FR(L + BHI, wc);      rBh[1] = FR(L + BHI, wc + 16);
#pragma unroll
    for (int i = 0; i < 4; ++i) rAh[i] = FR(L, wr + i * 16);
    rBl[0] = FR(L + BLO, wc);      rBl[1] = FR(L + BLO, wc + 16);
#pragma unroll
    for (int i = 0; i < 4; ++i) rAl[i] = FR(L + ALO, wr + i * 16);
    stA(sb, ks);
    asm volatile("s_barrier" ::: "memory");
    __builtin_amdgcn_s_setprio(1);
#pragma unroll
    for (int j = 0; j < 2; ++j)
#pragma unroll
      for (int i = 0; i < 4; ++i) acc[i][j] = mfma16(rAh[i], rBh[j], acc[i][j]);
#pragma unroll
    for (int j = 0; j < 2; ++j)
#pragma unroll
      for (int i = 0; i < 4; ++i) acc[i][j] = mfma16(rAh[i], rBl[j], acc[i][j]);
#pragma unroll
    for (int j = 0; j < 2; ++j)
#pragma unroll
      for (int i = 0; i < 4; ++i) acc[i][j] = mfma16(rAl[i], rBh[j], acc[i][j]);
    __builtin_amdgcn_s_setprio(0);
    asm volatile("s_barrier" ::: "memory");
    // ---- phase B: B[2..3]; MFMA m0123 x n23 (24); counted vmcnt at step end
    rBh[2] = FR(L + BHI, wc + 32); rBh[3] = FR(L + BHI, wc + 48);
    rBl[2] = FR(L + BLO, wc + 32); rBl[3] = FR(L + BLO, wc + 48);
    stB(sb, ks);
    asm volatile("s_barrier" ::: "memory");
    __builtin_amdgcn_s_setprio(1);
#pragma unroll
    for (int j = 2; j < 4; ++j)
#pragma unroll
      for (int i = 0; i < 4; ++i) acc[i][j] = mfma16(rAh[i], rBh[j], acc[i][j]);
#pragma unroll
    for (int j = 2; j < 4; ++j)
#pragma unroll
      for (int i = 0; i < 4; ++i) acc[i][j] = mfma16(rAh[i], rBl[j], acc[i][j]);
#pragma unroll
    for (int j = 2; j < 4; ++j)
#pragma unroll
      for (int i = 0; i < 4; ++i) acc[i][j] = mfma16(rAl[i], rBh[j], acc[i][j]);
    __builtin_amdgcn_s_setprio(0);
    asm volatile("s_waitcnt vmcnt(6)" ::: "memory"); // next step's loads landed
    asm volatile("s_barrier" ::: "memory");
  }
}

// ---------- kernel 1: split t/v/a -> packed hi|lo + transposed hi ----------
__global__ __launch_bounds__(256) void split_x_kernel(
    const float* __restrict__ v, const float* __restrict__ t, const float* __restrict__ a,
    ushort_t* __restrict__ xpack, ushort_t* __restrict__ xT) {
  __shared__ ushort_t tile[64][65];
  int mod = blockIdx.z;
  const float* src = (mod == 0) ? v : (mod == 1 ? t : a);
  int b = blockIdx.y;
  int s0 = (blockIdx.x >> 4) * 64;
  int f0 = (blockIdx.x & 15) * 64;
  int tid = threadIdx.x;
  ushort_t* xp = xpack + mod * (NX * 2);
  ushort_t* xt = xT + mod * NX;
  int fl = (tid & 15) * 4;
#pragma unroll
  for (int r = 0; r < 4; ++r) {
    int sl = (tid >> 4) + r * 16;
    int row = b * S + s0 + sl;
    float4 x = *(const float4*)(src + (size_t)row * F + f0 + fl);
    ushort_t h0 = f2bf(x.x), h1 = f2bf(x.y), h2 = f2bf(x.z), h3 = f2bf(x.w);
    size_t o = pk(row, f0 + fl, XP);
    *(ushort4*)(xp + o) = make_ushort4(h0, h1, h2, h3);
    *(ushort4*)(xp + o + 32) = make_ushort4(
        f2bf(x.x - bf2f(h0)), f2bf(x.y - bf2f(h1)),
        f2bf(x.z - bf2f(h2)), f2bf(x.w - bf2f(h3)));
    tile[sl][fl] = h0; tile[sl][fl + 1] = h1; tile[sl][fl + 2] = h2; tile[sl][fl + 3] = h3;
  }
  __syncthreads();
#pragma unroll
  for (int r = 0; r < 4; ++r) {
    int flr = (tid >> 4) + r * 16;
    int sl4 = (tid & 15) * 4;
    ushort4 o = make_ushort4(tile[sl4][flr], tile[sl4 + 1][flr],
                             tile[sl4 + 2][flr], tile[sl4 + 3][flr]);
    size_t tidx = ((size_t)(b * F + f0 + flr)) * S + s0 + sl4;
    *(ushort4*)(xt + tidx) = o;
  }
}

// ---------- kernel 2: W (2048x1024) -> WT packed hi|lo (1024 rows x K=2048) ----------
__global__ __launch_bounds__(256) void split_w_kernel(
    const float* __restrict__ w0, const float* __restrict__ w1, const float* __restrict__ w2,
    ushort_t* __restrict__ wtpack) {
  __shared__ ushort_t th[64][65];
  __shared__ ushort_t tl[64][65];
  int br = blockIdx.z;
  const float* w = (br == 0) ? w0 : (br == 1 ? w1 : w2);
  int g0 = blockIdx.x * 64;   // cols of W (rows of WT)
  int f0 = blockIdx.y * 64;   // rows of W (K dim)
  int tid = threadIdx.x;
  int gl = (tid & 15) * 4;
#pragma unroll
  for (int r = 0; r < 4; ++r) {
    int fl = (tid >> 4) + r * 16;
    float4 x = *(const float4*)(w + (size_t)(f0 + fl) * F + g0 + gl);
    ushort_t h0 = f2bf(x.x), h1 = f2bf(x.y), h2 = f2bf(x.z), h3 = f2bf(x.w);
    th[fl][gl] = h0; th[fl][gl + 1] = h1; th[fl][gl + 2] = h2; th[fl][gl + 3] = h3;
    tl[fl][gl] = f2bf(x.x - bf2f(h0));
    tl[fl][gl + 1] = f2bf(x.y - bf2f(h1));
    tl[fl][gl + 2] = f2bf(x.z - bf2f(h2));
    tl[fl][gl + 3] = f2bf(x.w - bf2f(h3));
  }
  __syncthreads();
  ushort_t* op = wtpack + br * (NW * 2);
#pragma unroll
  for (int r = 0; r < 4; ++r) {
    int glr = (tid >> 4) + r * 16;
    int fl4 = (tid & 15) * 4;
    size_t o = pk(g0 + glr, f0 + fl4, WP);
    *(ushort4*)(op + o) = make_ushort4(th[fl4][glr], th[fl4 + 1][glr],
                                       th[fl4 + 2][glr], th[fl4 + 3][glr]);
    *(ushort4*)(op + o + 32) = make_ushort4(tl[fl4][glr], tl[fl4 + 1][glr],
                                            tl[fl4 + 2][glr], tl[fl4 + 3][glr]);
  }
}

// ---------- kernel 3: Feat = tanh(concat(x1,x2) @ W + b) ----------
__global__ __launch_bounds__(512, 2) void feat_gemm8p_kernel(
    const ushort_t* __restrict__ xpack, const ushort_t* __restrict__ wtpack,
    const float* __restrict__ b0, const float* __restrict__ b1, const float* __restrict__ b2,
    ushort_t* __restrict__ fpack) {
  constexpr int M1[3] = {1, 1, 2};   // t, t, a
  constexpr int M2[3] = {0, 2, 0};   // v, a, v
  __shared__ __attribute__((aligned(16))) ushort_t lds[3 * 24576];   // 144 KB
  int br = blockIdx.z;
  int lin = blockIdx.x;
  // XCD-chunked: lin&7 = XCD (round-robin dispatch); 8 n-blocks sharing an
  // A-panel land on the SAME XCD -> A fetched once per panel into that L2.
  int gm0 = ((lin & 7) * 4 + (lin >> 6)) * 256;
  int gn0 = ((lin >> 3) & 7) * 128;
  int tid = threadIdx.x, lane = tid & 63, w = tid >> 6;
  const ushort_t* a1 = xpack + M1[br] * (NX * 2) + (size_t)gm0 * XP;
  const ushort_t* a2 = xpack + M2[br] * (NX * 2) + (size_t)gm0 * XP;
  const ushort_t* bb = wtpack + br * (NW * 2) + (size_t)gn0 * WP;
  f32x4 acc[4][4] = {};
  gemm8p_core<64, 32>(a1, a2, XP, bb, WP, lds, tid, acc);
  const float* bias = (br == 0) ? b0 : (br == 1 ? b1 : b2);
  ushort_t* op = fpack + br * (NX * 2);
  int wr = (w >> 1) * 64, wc = (w & 1) * 64;
#pragma unroll
  for (int i = 0; i < 4; ++i)
#pragma unroll
    for (int j = 0; j < 4; ++j)
#pragma unroll
      for (int r = 0; r < 4; ++r) {
        int row = gm0 + wr + i * 16 + (lane >> 4) * 4 + r;
        int col = gn0 + wc + j * 16 + (lane & 15);
        float val = tanhf(acc[i][j][r] + bias[col]);
        ushort_t h = f2bf(val);
        size_t o = pk(row, col, XP);
        op[o] = h;
        op[o + 32] = f2bf(val - bf2f(h));
      }
}

// ---------- kernel 4: scores = q @ feat^T, fp32 out ----------
__global__ __launch_bounds__(512, 2) void scores_gemm8p_kernel(
    const ushort_t* __restrict__ xpack, const ushort_t* __restrict__ fpack,
    float* __restrict__ scores) {
  constexpr int QM[3] = {2, 0, 1};   // a, v, t
  __shared__ __attribute__((aligned(16))) ushort_t lds[3 * 24576];
  int z = blockIdx.z;
  int br = z >> 4, b = z & 15;
  int gm0 = blockIdx.x * 256;
  int gn0 = blockIdx.y * 128;
  int tid = threadIdx.x, lane = tid & 63, w = tid >> 6;
  const ushort_t* a1 = xpack + QM[br] * (NX * 2) + (size_t)(b * S + gm0) * XP;
  const ushort_t* bb = fpack + br * (NX * 2) + (size_t)(b * S + gn0) * XP;
  f32x4 acc[4][4] = {};
  gemm8p_core<32, 32>(a1, a1, XP, bb, XP, lds, tid, acc);   // SPLIT_STEP=KSTEPS: a2 unused
  float* out = scores + (size_t)z * S * S;
  int wr = (w >> 1) * 64, wc = (w & 1) * 64;
#pragma unroll
  for (int i = 0; i < 4; ++i)
#pragma unroll
    for (int j = 0; j < 4; ++j)
#pragma unroll
      for (int r = 0; r < 4; ++r) {
        int row = gm0 + wr + i * 16 + (lane >> 4) * 4 + r;
        int col = gn0 + wc + j * 16 + (lane & 15);
        out[(size_t)row * S + col] = acc[i][j][r];
      }
}

// ---------- kernel 5: row softmax (512), fp32 in -> bf16 p ----------
__global__ __launch_bounds__(256) void softmax_kernel(
    const float* __restrict__ scores, ushort_t* __restrict__ p) {
  int wave = threadIdx.x >> 6, lane = threadIdx.x & 63;
  int row = blockIdx.x * 4 + wave;
  const float* src = scores + (size_t)row * S;
  float4 v0 = *(const float4*)(src + lane * 8);
  float4 v1 = *(const float4*)(src + lane * 8 + 4);
  float m = fmaxf(fmaxf(fmaxf(v0.x, v0.y), fmaxf(v0.z, v0.w)),
                  fmaxf(fmaxf(v1.x, v1.y), fmaxf(v1.z, v1.w)));
#pragma unroll
  for (int d = 1; d < 64; d <<= 1) m = fmaxf(m, __shfl_xor(m, d));
  float e[8] = {expf(v0.x - m), expf(v0.y - m), expf(v0.z - m), expf(v0.w - m),
                expf(v1.x - m), expf(v1.y - m), expf(v1.z - m), expf(v1.w - m)};
  float s = ((e[0] + e[1]) + (e[2] + e[3])) + ((e[4] + e[5]) + (e[6] + e[7]));
#pragma unroll
  for (int d = 1; d < 64; d <<= 1) s += __shfl_xor(s, d);
  float inv = 1.0f / s;
  u16x8 o;
#pragma unroll
  for (int j = 0; j < 8; ++j) o[j] = f2bf(e[j] * inv);
  *(u16x8*)(p + (size_t)row * S + lane * 8) = o;
}

// ---------- kernel 6: O = (p @ q) * feat, plain bf16 MFMA, fp32 out ----------
__global__ __launch_bounds__(256) void pv_gemm_kernel(
    const ushort_t* __restrict__ p, const ushort_t* __restrict__ xT,
    const ushort_t* __restrict__ fpack, float* __restrict__ out) {
  constexpr int QM[3] = {2, 0, 1};
  __shared__ __attribute__((aligned(16))) ushort_t lds[2 * 4096];
  ushort_t* Ah = lds;
  ushort_t* Bh = lds + 4096;
  int z = blockIdx.z;
  int br = z >> 4, b = z & 15;
  int gm0 = blockIdx.x * 128;
  int gn0 = blockIdx.y * 128;
  int tid = threadIdx.x, lane = tid & 63, wave = tid >> 6;
  int wr = (wave >> 1) * 64, wc = (wave & 1) * 64;
  const ushort_t* pa = p + (size_t)z * S * S;
  const ushort_t* qt = xT + QM[br] * NX + (size_t)b * F * S;   // [f][s]
  f32x4 acc[4][4] = {};
  for (int k0 = 0; k0 < S; k0 += 32) {
    stage_tile(Ah, pa + (size_t)gm0 * S + k0, S, tid);
    stage_tile(Bh, qt + (size_t)gn0 * S + k0, S, tid);
    __syncthreads();
    b16x8 af[4], bf_[4];
#pragma unroll
    for (int i = 0; i < 4; ++i) {
      af[i] = frag_ld(Ah, wr + i * 16, lane);
      bf_[i] = frag_ld(Bh, wc + i * 16, lane);
    }
#pragma unroll
    for (int i = 0; i < 4; ++i)
#pragma unroll
      for (int j = 0; j < 4; ++j)
        acc[i][j] = mfma16(af[i], bf_[j], acc[i][j]);
    __syncthreads();
  }
  const ushort_t* fp = fpack + br * (NX * 2);
#pragma unroll
  for (int i = 0; i < 4; ++i)
#pragma unroll
    for (int j = 0; j < 4; ++j)
#pragma unroll
      for (int r = 0; r < 4; ++r) {
        int row = gm0 + wr + i * 16 + (lane >> 4) * 4 + r;
        int col = gn0 + wc + j * 16 + (lane & 15);
        size_t fo = pk(b * S + row, col, XP);
        float fe = bf2f(fp[fo]) + bf2f(fp[fo + 32]);
        out[(size_t)(b * S + row) * (3 * F) + br * F + col] = acc[i][j][r] * fe;
      }
}

extern "C" void kernel_launch(void* const* d_in, const int* in_sizes, int n_in,
                              void* d_out, int out_size, void* d_ws, size_t ws_size,
                              hipStream_t stream) {
  (void)in_sizes; (void)n_in; (void)out_size; (void)ws_size;
  const float* v = (const float*)d_in[0];
  const float* t = (const float*)d_in[1];
  const float* a = (const float*)d_in[2];
  const float* W_tv = (const float*)d_in[3];
  const float* b_tv = (const float*)d_in[4];
  const float* W_ta = (const float*)d_in[5];
  const float* b_ta = (const float*)d_in[6];
  const float* W_av = (const float*)d_in[7];
  const float* b_av = (const float*)d_in[8];
  float* out = (float*)d_out;

  // ws layout (~352 MB total, same as R3)
  ushort_t* xpack = (ushort_t*)d_ws;            // 3 * NX*2
  ushort_t* xT = xpack + 3 * (NX * 2);          // 3 * NX
  ushort_t* wtpack = xT + 3 * NX;               // 3 * NW*2
  ushort_t* fpack = wtpack + 3 * (NW * 2);      // 3 * NX*2
  float* scores = (float*)(fpack + 3 * (NX * 2));
  ushort_t* pbuf = (ushort_t*)(scores + NSC);

  split_x_kernel<<<dim3(128, 16, 3), 256, 0, stream>>>(v, t, a, xpack, xT);
  split_w_kernel<<<dim3(16, 32, 3), 256, 0, stream>>>(W_tv, W_ta, W_av, wtpack);
  feat_gemm8p_kernel<<<dim3(256, 1, 3), 512, 0, stream>>>(xpack, wtpack,
                                                          b_tv, b_ta, b_av, fpack);
  scores_gemm8p_kernel<<<dim3(2, 4, 48), 512, 0, stream>>>(xpack, fpack, scores);
  softmax_kernel<<<dim3((3 * B * S) / 4), 256, 0, stream>>>(scores, pbuf);
  pv_gemm_kernel<<<dim3(4, 8, 48), 256, 0, stream>>>(pbuf, xT, fpack, out);
}

// Round 5
// 426.538 us; speedup vs baseline: 1.4040x; 1.2028x over previous
//
#include <hip/hip_runtime.h>

typedef unsigned short ushort_t;
typedef _Float16 f16x8 __attribute__((ext_vector_type(8)));
typedef float f32x4 __attribute__((ext_vector_type(4)));
typedef unsigned short u16x8 __attribute__((ext_vector_type(8)));

#define DEVINL __device__ __forceinline__

constexpr int B = 16, S = 512, F = 1024;
constexpr int M_ROWS = B * S;                    // 8192
constexpr size_t NX = (size_t)M_ROWS * F;        // 8,388,608 elems per modality
constexpr size_t NW = (size_t)F * (2 * F);       // 2,097,152 elems per branch
constexpr size_t NSC = (size_t)3 * B * S * S;    // 12,582,912 score elems

// packed pitch for split-x: per row, chunk c holds 32 hi at c*64, 32 lo at c*64+32
constexpr int XP = 2 * F;        // 2048

// ---------- fp16 helpers (RNE via v_cvt_f16_f32) ----------
DEVINL ushort_t f2h(float f) { return __builtin_bit_cast(ushort_t, (_Float16)f); }
DEVINL float h2f(ushort_t h) { return (float)__builtin_bit_cast(_Float16, h); }
// packed index of hi element (row, k); lo at +32
DEVINL size_t pk(int row, int k, int pitch) {
  return (size_t)row * pitch + ((k >> 5) * 64) + (k & 31);
}

// ---------- async global->LDS (16B per lane) ----------
DEVINL void gload_lds16(const void* g, void* l) {
  __builtin_amdgcn_global_load_lds(
      (__attribute__((address_space(1))) void*)(g),
      (__attribute__((address_space(3))) void*)(l), 16, 0, 0);
}

DEVINL f32x4 mfma16h(f16x8 a, f16x8 b, f32x4 c) {
  return __builtin_amdgcn_mfma_f32_16x16x32_f16(a, b, c, 0, 0, 0);
}

// ---------- 2-phase helpers (pv_gemm only) ----------
DEVINL void stage_tile(ushort_t* lds, const ushort_t* src, int ld, int tid) {
  int wave = tid >> 6;
#pragma unroll
  for (int it = 0; it < 2; ++it) {
    int c = it * 256 + tid;
    const ushort_t* g = src + (size_t)(c >> 2) * ld + (c & 3) * 8;
    ushort_t* l = lds + (size_t)(it * 256 + wave * 64) * 8;
    gload_lds16(g, l);
  }
}
DEVINL f16x8 frag_ld(const ushort_t* lds, int rb, int lane) {
  return *(const f16x8*)(lds + (size_t)(rb + (lane & 15)) * 32 + (lane >> 4) * 8);
}

// ================== barrier-light 2-term split-fp16 GEMM core ==================
// C[256x128] = (Ah+Al)*B^T, A packed hi|lo (fp16 Dekker split), B plain fp16.
// 8 waves (4M x 2N), wave-tile 64x64 = 4x4 frags of 16x16x32 f16, BK=32.
// LDS: 3 buffers x {Ah[256][32], Al[256][32], B[128][32]} = 3 x 40KB = 120KB.
// ONE barrier + one counted vmcnt(5) per K-step; NO intra-step barriers:
// staging at step t writes buf (t-1)%3, whose reads all executed before the
// end-of-(t-1) barrier; per-wave vmcnt before the barrier covers cross-wave.
// Waves on a SIMD drift within the step -> ds_read hides under MFMA.
template <int KSTEPS, int SPLIT_STEP>
DEVINL void gemm2t_core(const ushort_t* __restrict__ a1, const ushort_t* __restrict__ a2,
                        int lda, const ushort_t* __restrict__ bsrc, int ldb,
                        ushort_t* lds, int tid, f32x4 (&acc)[4][4]) {
  constexpr int BUFE = 20480, ALO = 8192, BOFF = 16384;
  const int lane = tid & 63, w = tid >> 6;
  const int wr = (w >> 1) * 64, wc = (w & 1) * 64;
  // staging: lane -> row (l>>2), 16B slot (l&3) XOR-swizzled by (row>>1)&3 on
  // the GLOBAL source; LDS dest stays linear (both-sides-or-neither rule).
  const int scol = (((lane & 3) ^ ((lane >> 3) & 3)) * 8);
  const size_t arow = (size_t)(w * 32 + (lane >> 2));
  const size_t brow = (size_t)(w * 16 + (lane >> 2));
  // ds_read: row rb+(lane&15), logical slot lane>>4 -> phys slot ^((row>>1)&3)
  const int foff = (lane & 15) * 32 + (((lane >> 4) ^ ((lane >> 1) & 3)) * 8);

  auto stA = [&](int sb, int ks) {
    const ushort_t* base = (ks < SPLIT_STEP) ? a1 : a2;
    int kk = ks & (SPLIT_STEP - 1);
    const ushort_t* s = base + arow * lda + kk * 64 + scol;
    ushort_t* dh = lds + sb * BUFE + w * 1024;
    gload_lds16(s, dh);
    gload_lds16(s + (size_t)16 * lda, dh + 512);
    gload_lds16(s + 32, dh + ALO);                    // lo: same 128B line as hi
    gload_lds16(s + 32 + (size_t)16 * lda, dh + ALO + 512);
  };
  auto stB = [&](int sb, int ks) {
    const ushort_t* s = bsrc + brow * ldb + ks * 32 + scol;
    gload_lds16(s, lds + sb * BUFE + BOFF + w * 512);
  };
  auto FR = [&](const ushort_t* rgn, int rb) -> f16x8 {
    return *(const f16x8*)(rgn + rb * 32 + foff);
  };

  // prologue: stage steps 0 and 1
  stA(0, 0); stB(0, 0);
  stA(1, 1); stB(1, 1);
  asm volatile("s_waitcnt vmcnt(5)" ::: "memory");   // step 0 landed
  asm volatile("s_barrier" ::: "memory");

  for (int t = 0; t < KSTEPS; ++t) {
    const int cb = t % 3, sb = (t + 2) % 3;
    const int ks = (t + 2) & (KSTEPS - 1);           // clamped tail keeps vmcnt uniform
    stA(sb, ks); stB(sb, ks);                        // issue early: HBM latency under MFMA
    const ushort_t* L = lds + cb * BUFE;
    f16x8 rB[4], rAh[4], rAl[4];
#pragma unroll
    for (int j = 0; j < 4; ++j) rB[j] = FR(L + BOFF, wc + j * 16);
#pragma unroll
    for (int i = 0; i < 4; ++i) rAh[i] = FR(L, wr + i * 16);
#pragma unroll
    for (int i = 0; i < 4; ++i) rAl[i] = FR(L + ALO, wr + i * 16);
    __builtin_amdgcn_s_setprio(1);
#pragma unroll
    for (int j = 0; j < 4; ++j)
#pragma unroll
      for (int i = 0; i < 4; ++i) acc[i][j] = mfma16h(rAh[i], rB[j], acc[i][j]);
#pragma unroll
    for (int j = 0; j < 4; ++j)
#pragma unroll
      for (int i = 0; i < 4; ++i) acc[i][j] = mfma16h(rAl[i], rB[j], acc[i][j]);
    __builtin_amdgcn_s_setprio(0);
    asm volatile("s_waitcnt vmcnt(5)" ::: "memory"); // step t+1's 5 loads landed
    asm volatile("s_barrier" ::: "memory");
  }
}

// ---------- kernel 1: split t/v/a -> packed fp16 hi|lo + transposed hi ----------
__global__ __launch_bounds__(256) void split_x_kernel(
    const float* __restrict__ v, const float* __restrict__ t, const float* __restrict__ a,
    ushort_t* __restrict__ xpack, ushort_t* __restrict__ xT) {
  __shared__ ushort_t tile[64][65];
  int mod = blockIdx.z;
  const float* src = (mod == 0) ? v : (mod == 1 ? t : a);
  int b = blockIdx.y;
  int s0 = (blockIdx.x >> 4) * 64;
  int f0 = (blockIdx.x & 15) * 64;
  int tid = threadIdx.x;
  ushort_t* xp = xpack + mod * (NX * 2);
  ushort_t* xt = xT + mod * NX;
  int fl = (tid & 15) * 4;
#pragma unroll
  for (int r = 0; r < 4; ++r) {
    int sl = (tid >> 4) + r * 16;
    int row = b * S + s0 + sl;
    float4 x = *(const float4*)(src + (size_t)row * F + f0 + fl);
    ushort_t h0 = f2h(x.x), h1 = f2h(x.y), h2 = f2h(x.z), h3 = f2h(x.w);
    size_t o = pk(row, f0 + fl, XP);
    *(ushort4*)(xp + o) = make_ushort4(h0, h1, h2, h3);
    *(ushort4*)(xp + o + 32) = make_ushort4(
        f2h(x.x - h2f(h0)), f2h(x.y - h2f(h1)),
        f2h(x.z - h2f(h2)), f2h(x.w - h2f(h3)));
    tile[sl][fl] = h0; tile[sl][fl + 1] = h1; tile[sl][fl + 2] = h2; tile[sl][fl + 3] = h3;
  }
  __syncthreads();
#pragma unroll
  for (int r = 0; r < 4; ++r) {
    int flr = (tid >> 4) + r * 16;
    int sl4 = (tid & 15) * 4;
    ushort4 o = make_ushort4(tile[sl4][flr], tile[sl4 + 1][flr],
                             tile[sl4 + 2][flr], tile[sl4 + 3][flr]);
    size_t tidx = ((size_t)(b * F + f0 + flr)) * S + s0 + sl4;
    *(ushort4*)(xt + tidx) = o;
  }
}

// ---------- kernel 2: W (2048x1024) -> WT plain fp16 (1024 rows x K=2048) ----------
__global__ __launch_bounds__(256) void split_w_kernel(
    const float* __restrict__ w0, const float* __restrict__ w1, const float* __restrict__ w2,
    ushort_t* __restrict__ wtpack) {
  __shared__ ushort_t th[64][65];
  int br = blockIdx.z;
  const float* w = (br == 0) ? w0 : (br == 1 ? w1 : w2);
  int g0 = blockIdx.x * 64;   // cols of W (rows of WT)
  int f0 = blockIdx.y * 64;   // rows of W (K dim)
  int tid = threadIdx.x;
  int gl = (tid & 15) * 4;
#pragma unroll
  for (int r = 0; r < 4; ++r) {
    int fl = (tid >> 4) + r * 16;
    float4 x = *(const float4*)(w + (size_t)(f0 + fl) * F + g0 + gl);
    th[fl][gl] = f2h(x.x); th[fl][gl + 1] = f2h(x.y);
    th[fl][gl + 2] = f2h(x.z); th[fl][gl + 3] = f2h(x.w);
  }
  __syncthreads();
  ushort_t* op = wtpack + br * NW;
#pragma unroll
  for (int r = 0; r < 4; ++r) {
    int glr = (tid >> 4) + r * 16;
    int fl4 = (tid & 15) * 4;
    size_t o = (size_t)(g0 + glr) * (2 * F) + f0 + fl4;
    *(ushort4*)(op + o) = make_ushort4(th[fl4][glr], th[fl4 + 1][glr],
                                       th[fl4 + 2][glr], th[fl4 + 3][glr]);
  }
}

// ---------- kernel 3: Feat = tanh(concat(x1,x2) @ W + b), fp16 out ----------
__global__ __launch_bounds__(512, 2) void feat_gemm_kernel(
    const ushort_t* __restrict__ xpack, const ushort_t* __restrict__ wtpack,
    const float* __restrict__ b0, const float* __restrict__ b1, const float* __restrict__ b2,
    ushort_t* __restrict__ fpack) {
  constexpr int M1[3] = {1, 1, 2};   // t, t, a
  constexpr int M2[3] = {0, 2, 0};   // v, a, v
  __shared__ __attribute__((aligned(16))) ushort_t lds[3 * 20480];   // 120 KB
  int br = blockIdx.z;
  int lin = blockIdx.x;
  // XCD-chunked: lin&7 = XCD; the 8 n-blocks sharing an A-panel land on the
  // SAME XCD (proven: FETCH 824->203MB in R3).
  int gm0 = ((lin & 7) * 4 + (lin >> 6)) * 256;
  int gn0 = ((lin >> 3) & 7) * 128;
  int tid = threadIdx.x, lane = tid & 63, w = tid >> 6;
  const ushort_t* a1 = xpack + M1[br] * (NX * 2) + (size_t)gm0 * XP;
  const ushort_t* a2 = xpack + M2[br] * (NX * 2) + (size_t)gm0 * XP;
  const ushort_t* bb = wtpack + br * NW + (size_t)gn0 * (2 * F);
  f32x4 acc[4][4] = {};
  gemm2t_core<64, 32>(a1, a2, XP, bb, 2 * F, lds, tid, acc);
  const float* bias = (br == 0) ? b0 : (br == 1 ? b1 : b2);
  ushort_t* op = fpack + br * NX;
  int wr = (w >> 1) * 64, wc = (w & 1) * 64;
#pragma unroll
  for (int i = 0; i < 4; ++i)
#pragma unroll
    for (int j = 0; j < 4; ++j)
#pragma unroll
      for (int r = 0; r < 4; ++r) {
        int row = gm0 + wr + i * 16 + (lane >> 4) * 4 + r;
        int col = gn0 + wc + j * 16 + (lane & 15);
        op[(size_t)row * F + col] = f2h(tanhf(acc[i][j][r] + bias[col]));
      }
}

// ---------- kernel 4: scores = q @ feat^T, fp32 out ----------
__global__ __launch_bounds__(512, 2) void scores_gemm_kernel(
    const ushort_t* __restrict__ xpack, const ushort_t* __restrict__ fpack,
    float* __restrict__ scores) {
  constexpr int QM[3] = {2, 0, 1};   // a, v, t
  __shared__ __attribute__((aligned(16))) ushort_t lds[3 * 20480];
  int z = blockIdx.z;
  int br = z >> 4, b = z & 15;
  int gm0 = blockIdx.x * 256;
  int gn0 = blockIdx.y * 128;
  int tid = threadIdx.x, lane = tid & 63, w = tid >> 6;
  const ushort_t* a1 = xpack + QM[br] * (NX * 2) + (size_t)(b * S + gm0) * XP;
  const ushort_t* bb = fpack + br * NX + (size_t)(b * S + gn0) * F;
  f32x4 acc[4][4] = {};
  gemm2t_core<32, 32>(a1, a1, XP, bb, F, lds, tid, acc);   // SPLIT_STEP=KSTEPS: a2 unused
  float* out = scores + (size_t)z * S * S;
  int wr = (w >> 1) * 64, wc = (w & 1) * 64;
#pragma unroll
  for (int i = 0; i < 4; ++i)
#pragma unroll
    for (int j = 0; j < 4; ++j)
#pragma unroll
      for (int r = 0; r < 4; ++r) {
        int row = gm0 + wr + i * 16 + (lane >> 4) * 4 + r;
        int col = gn0 + wc + j * 16 + (lane & 15);
        out[(size_t)row * S + col] = acc[i][j][r];
      }
}

// ---------- kernel 5: row softmax (512), fp32 in -> fp16 p ----------
__global__ __launch_bounds__(256) void softmax_kernel(
    const float* __restrict__ scores, ushort_t* __restrict__ p) {
  int wave = threadIdx.x >> 6, lane = threadIdx.x & 63;
  int row = blockIdx.x * 4 + wave;
  const float* src = scores + (size_t)row * S;
  float4 v0 = *(const float4*)(src + lane * 8);
  float4 v1 = *(const float4*)(src + lane * 8 + 4);
  float m = fmaxf(fmaxf(fmaxf(v0.x, v0.y), fmaxf(v0.z, v0.w)),
                  fmaxf(fmaxf(v1.x, v1.y), fmaxf(v1.z, v1.w)));
#pragma unroll
  for (int d = 1; d < 64; d <<= 1) m = fmaxf(m, __shfl_xor(m, d));
  float e[8] = {expf(v0.x - m), expf(v0.y - m), expf(v0.z - m), expf(v0.w - m),
                expf(v1.x - m), expf(v1.y - m), expf(v1.z - m), expf(v1.w - m)};
  float s = ((e[0] + e[1]) + (e[2] + e[3])) + ((e[4] + e[5]) + (e[6] + e[7]));
#pragma unroll
  for (int d = 1; d < 64; d <<= 1) s += __shfl_xor(s, d);
  float inv = 1.0f / s;
  u16x8 o;
#pragma unroll
  for (int j = 0; j < 8; ++j) o[j] = f2h(e[j] * inv);
  *(u16x8*)(p + (size_t)row * S + lane * 8) = o;
}

// ---------- kernel 6: O = (p @ q) * feat, plain fp16 MFMA, fp32 out ----------
__global__ __launch_bounds__(256) void pv_gemm_kernel(
    const ushort_t* __restrict__ p, const ushort_t* __restrict__ xT,
    const ushort_t* __restrict__ fpack, float* __restrict__ out) {
  constexpr int QM[3] = {2, 0, 1};
  __shared__ __attribute__((aligned(16))) ushort_t lds[2 * 4096];
  ushort_t* Ah = lds;
  ushort_t* Bh = lds + 4096;
  int z = blockIdx.z;
  int br = z >> 4, b = z & 15;
  int gm0 = blockIdx.x * 128;
  int gn0 = blockIdx.y * 128;
  int tid = threadIdx.x, lane = tid & 63, wave = tid >> 6;
  int wr = (wave >> 1) * 64, wc = (wave & 1) * 64;
  const ushort_t* pa = p + (size_t)z * S * S;
  const ushort_t* qt = xT + QM[br] * NX + (size_t)b * F * S;   // [f][s]
  f32x4 acc[4][4] = {};
  for (int k0 = 0; k0 < S; k0 += 32) {
    stage_tile(Ah, pa + (size_t)gm0 * S + k0, S, tid);
    stage_tile(Bh, qt + (size_t)gn0 * S + k0, S, tid);
    __syncthreads();
    f16x8 af[4], bf_[4];
#pragma unroll
    for (int i = 0; i < 4; ++i) {
      af[i] = frag_ld(Ah, wr + i * 16, lane);
      bf_[i] = frag_ld(Bh, wc + i * 16, lane);
    }
#pragma unroll
    for (int i = 0; i < 4; ++i)
#pragma unroll
      for (int j = 0; j < 4; ++j)
        acc[i][j] = mfma16h(af[i], bf_[j], acc[i][j]);
    __syncthreads();
  }
  const ushort_t* fp = fpack + br * NX;
#pragma unroll
  for (int i = 0; i < 4; ++i)
#pragma unroll
    for (int j = 0; j < 4; ++j)
#pragma unroll
      for (int r = 0; r < 4; ++r) {
        int row = gm0 + wr + i * 16 + (lane >> 4) * 4 + r;
        int col = gn0 + wc + j * 16 + (lane & 15);
        float fe = h2f(fp[(size_t)(b * S + row) * F + col]);
        out[(size_t)(b * S + row) * (3 * F) + br * F + col] = acc[i][j][r] * fe;
      }
}

extern "C" void kernel_launch(void* const* d_in, const int* in_sizes, int n_in,
                              void* d_out, int out_size, void* d_ws, size_t ws_size,
                              hipStream_t stream) {
  (void)in_sizes; (void)n_in; (void)out_size; (void)ws_size;
  const float* v = (const float*)d_in[0];
  const float* t = (const float*)d_in[1];
  const float* a = (const float*)d_in[2];
  const float* W_tv = (const float*)d_in[3];
  const float* b_tv = (const float*)d_in[4];
  const float* W_ta = (const float*)d_in[5];
  const float* b_ta = (const float*)d_in[6];
  const float* W_av = (const float*)d_in[7];
  const float* b_av = (const float*)d_in[8];
  float* out = (float*)d_out;

  // ws layout (~290 MB total)
  ushort_t* xpack = (ushort_t*)d_ws;            // 3 * NX*2 (fp16 hi|lo packed)
  ushort_t* xT = xpack + 3 * (NX * 2);          // 3 * NX (fp16 plain, [f][s])
  ushort_t* wtpack = xT + 3 * NX;               // 3 * NW (fp16 plain)
  ushort_t* fpack = wtpack + 3 * NW;            // 3 * NX (fp16 plain)
  float* scores = (float*)(fpack + 3 * NX);
  ushort_t* pbuf = (ushort_t*)(scores + NSC);

  split_x_kernel<<<dim3(128, 16, 3), 256, 0, stream>>>(v, t, a, xpack, xT);
  split_w_kernel<<<dim3(16, 32, 3), 256, 0, stream>>>(W_tv, W_ta, W_av, wtpack);
  feat_gemm_kernel<<<dim3(256, 1, 3), 512, 0, stream>>>(xpack, wtpack,
                                                        b_tv, b_ta, b_av, fpack);
  scores_gemm_kernel<<<dim3(2, 4, 48), 512, 0, stream>>>(xpack, fpack, scores);
  softmax_kernel<<<dim3((3 * B * S) / 4), 256, 0, stream>>>(scores, pbuf);
  pv_gemm_kernel<<<dim3(4, 8, 48), 256, 0, stream>>>(pbuf, xT, fpack, out);
}

// Round 6
// 411.540 us; speedup vs baseline: 1.4552x; 1.0364x over previous
//
#include <hip/hip_runtime.h>

typedef unsigned short ushort_t;
typedef _Float16 f16x8 __attribute__((ext_vector_type(8)));
typedef float f32x4 __attribute__((ext_vector_type(4)));
typedef unsigned short u16x8 __attribute__((ext_vector_type(8)));

#define DEVINL __device__ __forceinline__

constexpr int B = 16, S = 512, F = 1024;
constexpr int M_ROWS = B * S;                    // 8192
constexpr size_t NX = (size_t)M_ROWS * F;        // 8,388,608 elems per modality
constexpr size_t NW = (size_t)F * (2 * F);       // 2,097,152 elems per branch
constexpr size_t NSC = (size_t)3 * B * S * S;    // 12,582,912 score elems

// packed pitch for split-x: per row, chunk c holds 32 hi at c*64, 32 lo at c*64+32
constexpr int XP = 2 * F;        // 2048

// ---------- fp16 helpers ----------
DEVINL ushort_t f2h(float f) { return __builtin_bit_cast(ushort_t, (_Float16)f); }
DEVINL float h2f(ushort_t h) { return (float)__builtin_bit_cast(_Float16, h); }
DEVINL size_t pk(int row, int k, int pitch) {
  return (size_t)row * pitch + ((k >> 5) * 64) + (k & 31);
}

// ---------- async global->LDS (16B per lane) ----------
DEVINL void gload_lds16(const void* g, void* l) {
  __builtin_amdgcn_global_load_lds(
      (__attribute__((address_space(1))) void*)(g),
      (__attribute__((address_space(3))) void*)(l), 16, 0, 0);
}

DEVINL f32x4 mfma16h(f16x8 a, f16x8 b, f32x4 c) {
  return __builtin_amdgcn_mfma_f32_16x16x32_f16(a, b, c, 0, 0, 0);
}

// ================== barrier-light 256x256 GEMM core ==================
// C[256x256] = (Ah[+Al]) * B^T; A optionally 2-term fp16 Dekker split (packed
// hi|lo), B plain fp16 row-major [N][K]. 8 waves as 4M x 2N, wave-tile 64x128
// = 4x8 frags of 16x16x32 f16, BK=32.
// LDS: 3 buffers x {Ah[256][32], (Al), B[256][32]} = 144 KB (TERMS=2) / 96 KB.
// ONE barrier + one counted vmcnt per K-step (no intra-step barriers; waves
// drift so ds_read+staging hide under MFMA). 6 (or 4) loads/wave/step,
// depth-2 prefetch. Race safety: buffer sb=(t+2)%3 was fully consumed at step
// t-1 (reads returned before that step's barrier); staging writes for sb are
// issued only after that barrier.
template <int KSTEPS, int SPLIT_STEP, int TERMS>
DEVINL void gemm_core(const ushort_t* __restrict__ a1, const ushort_t* __restrict__ a2,
                      int lda, const ushort_t* __restrict__ bsrc, int ldb,
                      ushort_t* lds, int tid, f32x4 (&acc)[4][8]) {
  constexpr int BUFE = (TERMS == 2) ? 24576 : 16384;
  constexpr int ALO = 8192;
  constexpr int BOFF = (TERMS == 2) ? 16384 : 8192;
  const int lane = tid & 63, w = tid >> 6;
  const int wr = (w >> 1) * 64, wc = (w & 1) * 128;
  // staging: lane -> row (l>>2), 16B slot (l&3) XOR-swizzled by (row>>1)&3 on
  // the GLOBAL source; LDS dest linear (both-sides-or-neither rule).
  const int scol = (((lane & 3) ^ ((lane >> 3) & 3)) * 8);
  const size_t grow = (size_t)(w * 32 + (lane >> 2));   // A and B both 256 rows
  // ds_read: row rb+(lane&15), logical slot lane>>4 -> phys ^((row>>1)&3)
  const int foff = (lane & 15) * 32 + (((lane >> 4) ^ ((lane >> 1) & 3)) * 8);

  auto stA = [&](int sb, int ks) {
    const ushort_t* base = (ks < SPLIT_STEP) ? a1 : a2;
    int kk = ks & (SPLIT_STEP - 1);
    ushort_t* dh = lds + sb * BUFE + w * 1024;
    if constexpr (TERMS == 2) {
      const ushort_t* s = base + grow * lda + kk * 64 + scol;
      gload_lds16(s, dh);
      gload_lds16(s + (size_t)16 * lda, dh + 512);
      gload_lds16(s + 32, dh + ALO);                    // lo: same 128B line
      gload_lds16(s + 32 + (size_t)16 * lda, dh + ALO + 512);
    } else {
      const ushort_t* s = base + grow * lda + ks * 32 + scol;
      gload_lds16(s, dh);
      gload_lds16(s + (size_t)16 * lda, dh + 512);
    }
  };
  auto stB = [&](int sb, int ks) {
    const ushort_t* s = bsrc + grow * ldb + ks * 32 + scol;
    ushort_t* d = lds + sb * BUFE + BOFF + w * 1024;
    gload_lds16(s, d);
    gload_lds16(s + (size_t)16 * ldb, d + 512);
  };
  auto FR = [&](const ushort_t* rgn, int rb) -> f16x8 {
    return *(const f16x8*)(rgn + rb * 32 + foff);
  };
  auto VMW = [&]() {
    if constexpr (TERMS == 2) asm volatile("s_waitcnt vmcnt(6)" ::: "memory");
    else                      asm volatile("s_waitcnt vmcnt(4)" ::: "memory");
  };

  // prologue: stage steps 0 and 1
  stA(0, 0); stB(0, 0);
  stA(1, 1); stB(1, 1);
  VMW();                                               // step 0 landed
  asm volatile("s_barrier" ::: "memory");

  for (int t = 0; t < KSTEPS; ++t) {
    const int cb = t % 3, sb = (t + 2) % 3;
    const int ks = (t + 2) & (KSTEPS - 1);             // clamped tail: uniform vmcnt
    stA(sb, ks); stB(sb, ks);                          // issue early (T14)
    const ushort_t* L = lds + cb * BUFE;
    f16x8 rAh[4], rAl[4], rB[8];
#pragma unroll
    for (int i = 0; i < 4; ++i) rAh[i] = FR(L, wr + i * 16);
#pragma unroll
    for (int j = 0; j < 8; ++j) rB[j] = FR(L + BOFF, wc + j * 16);
    if constexpr (TERMS == 2) {
#pragma unroll
      for (int i = 0; i < 4; ++i) rAl[i] = FR(L + ALO, wr + i * 16);
    }
    __builtin_amdgcn_s_setprio(1);
#pragma unroll
    for (int j = 0; j < 8; ++j)
#pragma unroll
      for (int i = 0; i < 4; ++i) acc[i][j] = mfma16h(rAh[i], rB[j], acc[i][j]);
    if constexpr (TERMS == 2) {
#pragma unroll
      for (int j = 0; j < 8; ++j)
#pragma unroll
        for (int i = 0; i < 4; ++i) acc[i][j] = mfma16h(rAl[i], rB[j], acc[i][j]);
    }
    __builtin_amdgcn_s_setprio(0);
    VMW();                                             // step t+1's loads landed
    asm volatile("s_barrier" ::: "memory");
  }
}

// ---------- kernel 1: split t/v/a -> packed fp16 hi|lo + transposed hi ----------
__global__ __launch_bounds__(256) void split_x_kernel(
    const float* __restrict__ v, const float* __restrict__ t, const float* __restrict__ a,
    ushort_t* __restrict__ xpack, ushort_t* __restrict__ xT) {
  __shared__ ushort_t tile[64][65];
  int mod = blockIdx.z;
  const float* src = (mod == 0) ? v : (mod == 1 ? t : a);
  int b = blockIdx.y;
  int s0 = (blockIdx.x >> 4) * 64;
  int f0 = (blockIdx.x & 15) * 64;
  int tid = threadIdx.x;
  ushort_t* xp = xpack + mod * (NX * 2);
  ushort_t* xt = xT + mod * NX;
  int fl = (tid & 15) * 4;
#pragma unroll
  for (int r = 0; r < 4; ++r) {
    int sl = (tid >> 4) + r * 16;
    int row = b * S + s0 + sl;
    float4 x = *(const float4*)(src + (size_t)row * F + f0 + fl);
    ushort_t h0 = f2h(x.x), h1 = f2h(x.y), h2 = f2h(x.z), h3 = f2h(x.w);
    size_t o = pk(row, f0 + fl, XP);
    *(ushort4*)(xp + o) = make_ushort4(h0, h1, h2, h3);
    *(ushort4*)(xp + o + 32) = make_ushort4(
        f2h(x.x - h2f(h0)), f2h(x.y - h2f(h1)),
        f2h(x.z - h2f(h2)), f2h(x.w - h2f(h3)));
    tile[sl][fl] = h0; tile[sl][fl + 1] = h1; tile[sl][fl + 2] = h2; tile[sl][fl + 3] = h3;
  }
  __syncthreads();
#pragma unroll
  for (int r = 0; r < 4; ++r) {
    int flr = (tid >> 4) + r * 16;
    int sl4 = (tid & 15) * 4;
    ushort4 o = make_ushort4(tile[sl4][flr], tile[sl4 + 1][flr],
                             tile[sl4 + 2][flr], tile[sl4 + 3][flr]);
    size_t tidx = ((size_t)(b * F + f0 + flr)) * S + s0 + sl4;
    *(ushort4*)(xt + tidx) = o;
  }
}

// ---------- kernel 2: W (2048x1024) -> WT plain fp16 (1024 rows x K=2048) ----------
__global__ __launch_bounds__(256) void split_w_kernel(
    const float* __restrict__ w0, const float* __restrict__ w1, const float* __restrict__ w2,
    ushort_t* __restrict__ wtpack) {
  __shared__ ushort_t th[64][65];
  int br = blockIdx.z;
  const float* w = (br == 0) ? w0 : (br == 1 ? w1 : w2);
  int g0 = blockIdx.x * 64;
  int f0 = blockIdx.y * 64;
  int tid = threadIdx.x;
  int gl = (tid & 15) * 4;
#pragma unroll
  for (int r = 0; r < 4; ++r) {
    int fl = (tid >> 4) + r * 16;
    float4 x = *(const float4*)(w + (size_t)(f0 + fl) * F + g0 + gl);
    th[fl][gl] = f2h(x.x); th[fl][gl + 1] = f2h(x.y);
    th[fl][gl + 2] = f2h(x.z); th[fl][gl + 3] = f2h(x.w);
  }
  __syncthreads();
  ushort_t* op = wtpack + br * NW;
#pragma unroll
  for (int r = 0; r < 4; ++r) {
    int glr = (tid >> 4) + r * 16;
    int fl4 = (tid & 15) * 4;
    size_t o = (size_t)(g0 + glr) * (2 * F) + f0 + fl4;
    *(ushort4*)(op + o) = make_ushort4(th[fl4][glr], th[fl4 + 1][glr],
                                       th[fl4 + 2][glr], th[fl4 + 3][glr]);
  }
}

// ---------- kernel 3: Feat = tanh(concat(x1,x2) @ W + b), fp16 out ----------
__global__ __launch_bounds__(512, 2) void feat_gemm_kernel(
    const ushort_t* __restrict__ xpack, const ushort_t* __restrict__ wtpack,
    const float* __restrict__ b0, const float* __restrict__ b1, const float* __restrict__ b2,
    ushort_t* __restrict__ fpack) {
  constexpr int M1[3] = {1, 1, 2};   // t, t, a
  constexpr int M2[3] = {0, 2, 0};   // v, a, v
  __shared__ __attribute__((aligned(16))) ushort_t lds[3 * 24576];   // 144 KB
  int br = blockIdx.z;
  int lin = blockIdx.x;              // 0..127
  // XCD-chunked: lin&7 = XCD; the 4 gn-blocks sharing an A-panel-pair sit on
  // the SAME XCD (lin, +32, +64, +96 all have equal lin&7).
  int gm0 = ((lin & 7) * 4 + ((lin >> 3) & 3)) * 256;
  int gn0 = (lin >> 5) * 256;
  int tid = threadIdx.x, lane = tid & 63, w = tid >> 6;
  const ushort_t* a1 = xpack + M1[br] * (NX * 2) + (size_t)gm0 * XP;
  const ushort_t* a2 = xpack + M2[br] * (NX * 2) + (size_t)gm0 * XP;
  const ushort_t* bb = wtpack + br * NW + (size_t)gn0 * (2 * F);
  f32x4 acc[4][8] = {};
  gemm_core<64, 32, 2>(a1, a2, XP, bb, 2 * F, lds, tid, acc);
  const float* bias = (br == 0) ? b0 : (br == 1 ? b1 : b2);
  ushort_t* op = fpack + br * NX;
  int wr = (w >> 1) * 64, wc = (w & 1) * 128;
#pragma unroll
  for (int i = 0; i < 4; ++i)
#pragma unroll
    for (int j = 0; j < 8; ++j)
#pragma unroll
      for (int r = 0; r < 4; ++r) {
        int row = gm0 + wr + i * 16 + (lane >> 4) * 4 + r;
        int col = gn0 + wc + j * 16 + (lane & 15);
        op[(size_t)row * F + col] = f2h(tanhf(acc[i][j][r] + bias[col]));
      }
}

// ---------- kernel 4: scores = q @ feat^T, fp32 out ----------
__global__ __launch_bounds__(512, 2) void scores_gemm_kernel(
    const ushort_t* __restrict__ xpack, const ushort_t* __restrict__ fpack,
    float* __restrict__ scores) {
  constexpr int QM[3] = {2, 0, 1};   // a, v, t
  __shared__ __attribute__((aligned(16))) ushort_t lds[3 * 24576];
  int z = blockIdx.z;
  int br = z >> 4, b = z & 15;
  int gm0 = blockIdx.x * 256;
  int gn0 = blockIdx.y * 256;
  int tid = threadIdx.x, lane = tid & 63, w = tid >> 6;
  const ushort_t* a1 = xpack + QM[br] * (NX * 2) + (size_t)(b * S + gm0) * XP;
  const ushort_t* bb = fpack + br * NX + (size_t)(b * S + gn0) * F;
  f32x4 acc[4][8] = {};
  gemm_core<32, 32, 2>(a1, a1, XP, bb, F, lds, tid, acc);
  float* out = scores + (size_t)z * S * S;
  int wr = (w >> 1) * 64, wc = (w & 1) * 128;
#pragma unroll
  for (int i = 0; i < 4; ++i)
#pragma unroll
    for (int j = 0; j < 8; ++j)
#pragma unroll
      for (int r = 0; r < 4; ++r) {
        int row = gm0 + wr + i * 16 + (lane >> 4) * 4 + r;
        int col = gn0 + wc + j * 16 + (lane & 15);
        out[(size_t)row * S + col] = acc[i][j][r];
      }
}

// ---------- kernel 5: row softmax (512), fp32 in -> fp16 p ----------
__global__ __launch_bounds__(256) void softmax_kernel(
    const float* __restrict__ scores, ushort_t* __restrict__ p) {
  int wave = threadIdx.x >> 6, lane = threadIdx.x & 63;
  int row = blockIdx.x * 4 + wave;
  const float* src = scores + (size_t)row * S;
  float4 v0 = *(const float4*)(src + lane * 8);
  float4 v1 = *(const float4*)(src + lane * 8 + 4);
  float m = fmaxf(fmaxf(fmaxf(v0.x, v0.y), fmaxf(v0.z, v0.w)),
                  fmaxf(fmaxf(v1.x, v1.y), fmaxf(v1.z, v1.w)));
#pragma unroll
  for (int d = 1; d < 64; d <<= 1) m = fmaxf(m, __shfl_xor(m, d));
  float e[8] = {expf(v0.x - m), expf(v0.y - m), expf(v0.z - m), expf(v0.w - m),
                expf(v1.x - m), expf(v1.y - m), expf(v1.z - m), expf(v1.w - m)};
  float s = ((e[0] + e[1]) + (e[2] + e[3])) + ((e[4] + e[5]) + (e[6] + e[7]));
#pragma unroll
  for (int d = 1; d < 64; d <<= 1) s += __shfl_xor(s, d);
  float inv = 1.0f / s;
  u16x8 o;
#pragma unroll
  for (int j = 0; j < 8; ++j) o[j] = f2h(e[j] * inv);
  *(u16x8*)(p + (size_t)row * S + lane * 8) = o;
}

// ---------- kernel 6: O = (p @ q) * feat, fp32 out ----------
__global__ __launch_bounds__(512, 2) void pv_gemm_kernel(
    const ushort_t* __restrict__ p, const ushort_t* __restrict__ xT,
    const ushort_t* __restrict__ fpack, float* __restrict__ out) {
  constexpr int QM[3] = {2, 0, 1};
  __shared__ __attribute__((aligned(16))) ushort_t lds[3 * 16384];   // 96 KB
  int z = blockIdx.z;
  int br = z >> 4, b = z & 15;
  int gm0 = blockIdx.x * 256;
  int gn0 = blockIdx.y * 256;
  int tid = threadIdx.x, lane = tid & 63, w = tid >> 6;
  const ushort_t* pa = p + (size_t)z * S * S + (size_t)gm0 * S;
  const ushort_t* qt = xT + QM[br] * NX + (size_t)b * F * S + (size_t)gn0 * S;  // [f][s]
  f32x4 acc[4][8] = {};
  gemm_core<16, 16, 1>(pa, pa, S, qt, S, lds, tid, acc);
  const ushort_t* fp = fpack + br * NX;
  int wr = (w >> 1) * 64, wc = (w & 1) * 128;
#pragma unroll
  for (int i = 0; i < 4; ++i)
#pragma unroll
    for (int j = 0; j < 8; ++j)
#pragma unroll
      for (int r = 0; r < 4; ++r) {
        int row = gm0 + wr + i * 16 + (lane >> 4) * 4 + r;
        int col = gn0 + wc + j * 16 + (lane & 15);
        float fe = h2f(fp[(size_t)(b * S + row) * F + col]);
        out[(size_t)(b * S + row) * (3 * F) + br * F + col] = acc[i][j][r] * fe;
      }
}

extern "C" void kernel_launch(void* const* d_in, const int* in_sizes, int n_in,
                              void* d_out, int out_size, void* d_ws, size_t ws_size,
                              hipStream_t stream) {
  (void)in_sizes; (void)n_in; (void)out_size; (void)ws_size;
  const float* v = (const float*)d_in[0];
  const float* t = (const float*)d_in[1];
  const float* a = (const float*)d_in[2];
  const float* W_tv = (const float*)d_in[3];
  const float* b_tv = (const float*)d_in[4];
  const float* W_ta = (const float*)d_in[5];
  const float* b_ta = (const float*)d_in[6];
  const float* W_av = (const float*)d_in[7];
  const float* b_av = (const float*)d_in[8];
  float* out = (float*)d_out;

  // ws layout (~290 MB total)
  ushort_t* xpack = (ushort_t*)d_ws;            // 3 * NX*2 (fp16 hi|lo packed)
  ushort_t* xT = xpack + 3 * (NX * 2);          // 3 * NX (fp16 plain, [f][s])
  ushort_t* wtpack = xT + 3 * NX;               // 3 * NW (fp16 plain)
  ushort_t* fpack = wtpack + 3 * NW;            // 3 * NX (fp16 plain)
  float* scores = (float*)(fpack + 3 * NX);
  ushort_t* pbuf = (ushort_t*)(scores + NSC);

  split_x_kernel<<<dim3(128, 16, 3), 256, 0, stream>>>(v, t, a, xpack, xT);
  split_w_kernel<<<dim3(16, 32, 3), 256, 0, stream>>>(W_tv, W_ta, W_av, wtpack);
  feat_gemm_kernel<<<dim3(128, 1, 3), 512, 0, stream>>>(xpack, wtpack,
                                                        b_tv, b_ta, b_av, fpack);
  scores_gemm_kernel<<<dim3(2, 2, 48), 512, 0, stream>>>(xpack, fpack, scores);
  softmax_kernel<<<dim3((3 * B * S) / 4), 256, 0, stream>>>(scores, pbuf);
  pv_gemm_kernel<<<dim3(2, 4, 48), 512, 0, stream>>>(pbuf, xT, fpack, out);
}

// Round 7
// 339.247 us; speedup vs baseline: 1.7653x; 1.2131x over previous
//
#include <hip/hip_runtime.h>

typedef unsigned short ushort_t;
typedef _Float16 f16x8 __attribute__((ext_vector_type(8)));
typedef float f32x4 __attribute__((ext_vector_type(4)));
typedef unsigned short u16x8 __attribute__((ext_vector_type(8)));

#define DEVINL __device__ __forceinline__

constexpr int B = 16, S = 512, F = 1024;
constexpr int M_ROWS = B * S;                    // 8192
constexpr size_t NX = (size_t)M_ROWS * F;        // 8,388,608 elems per modality
constexpr size_t NW = (size_t)F * (2 * F);       // 2,097,152 elems per branch
constexpr size_t NSC = (size_t)3 * B * S * S;    // 12,582,912 score elems

// packed pitch for split-x: per row, chunk c holds 32 hi at c*64, 32 lo at c*64+32
constexpr int XP = 2 * F;        // 2048

// ---------- fp16 helpers ----------
DEVINL ushort_t f2h(float f) { return __builtin_bit_cast(ushort_t, (_Float16)f); }
DEVINL float h2f(ushort_t h) { return (float)__builtin_bit_cast(_Float16, h); }
DEVINL size_t pk(int row, int k, int pitch) {
  return (size_t)row * pitch + ((k >> 5) * 64) + (k & 31);
}

// ---------- async global->LDS (16B per lane) ----------
DEVINL void gload_lds16(const void* g, void* l) {
  __builtin_amdgcn_global_load_lds(
      (__attribute__((address_space(1))) void*)(g),
      (__attribute__((address_space(3))) void*)(l), 16, 0, 0);
}

DEVINL f32x4 mfma16h(f16x8 a, f16x8 b, f32x4 c) {
  return __builtin_amdgcn_mfma_f32_16x16x32_f16(a, b, c, 0, 0, 0);
}

// ================== barrier-light 256x256 GEMM core ==================
// C[256x256] = (Ah[+Al]) * B^T; A optionally 2-term fp16 Dekker split, B plain
// fp16 row-major [N][K]. 8 waves as 4M x 2N, wave-tile 64x128 = 4x8 frags of
// 16x16x32 f16, BK=32.
// KCHUNK = element stride of one BK=32 A-chunk in the source row: 64 for the
// packed hi|lo layout (TERMS=2 reads hi+lo; TERMS=1 reads hi only), 32 plain.
// LDS: 3 buffers x {Ah[256][32], (Al), B[256][32]}: 144/96 KB.
// ONE barrier + one counted vmcnt per K-step (no intra-step barriers; waves
// drift so ds_read+staging hide under MFMA). Depth-2 prefetch. Race safety:
// buffer sb=(t+2)%3 was fully consumed at step t-1 (reads returned before
// that step's barrier); staging writes for sb are issued only after it.
template <int KSTEPS, int SPLIT_STEP, int TERMS, int KCHUNK>
DEVINL void gemm_core(const ushort_t* __restrict__ a1, const ushort_t* __restrict__ a2,
                      int lda, const ushort_t* __restrict__ bsrc, int ldb,
                      ushort_t* lds, int tid, f32x4 (&acc)[4][8]) {
  constexpr int BUFE = (TERMS == 2) ? 24576 : 16384;
  constexpr int ALO = 8192;
  constexpr int BOFF = (TERMS == 2) ? 16384 : 8192;
  const int lane = tid & 63, w = tid >> 6;
  const int wr = (w >> 1) * 64, wc = (w & 1) * 128;
  // staging: lane -> row (l>>2), 16B slot (l&3) XOR-swizzled by (row>>1)&3 on
  // the GLOBAL source; LDS dest linear (both-sides-or-neither rule).
  const int scol = (((lane & 3) ^ ((lane >> 3) & 3)) * 8);
  const size_t grow = (size_t)(w * 32 + (lane >> 2));   // A and B both 256 rows
  // ds_read: row rb+(lane&15), logical slot lane>>4 -> phys ^((row>>1)&3)
  const int foff = (lane & 15) * 32 + (((lane >> 4) ^ ((lane >> 1) & 3)) * 8);

  auto stA = [&](int sb, int ks) {
    const ushort_t* base = (ks < SPLIT_STEP) ? a1 : a2;
    int kk = ks & (SPLIT_STEP - 1);
    const ushort_t* s = base + grow * lda + kk * KCHUNK + scol;
    ushort_t* dh = lds + sb * BUFE + w * 1024;
    gload_lds16(s, dh);
    gload_lds16(s + (size_t)16 * lda, dh + 512);
    if constexpr (TERMS == 2) {
      gload_lds16(s + 32, dh + ALO);                    // lo: same 128B line
      gload_lds16(s + 32 + (size_t)16 * lda, dh + ALO + 512);
    }
  };
  auto stB = [&](int sb, int ks) {
    const ushort_t* s = bsrc + grow * ldb + ks * 32 + scol;
    ushort_t* d = lds + sb * BUFE + BOFF + w * 1024;
    gload_lds16(s, d);
    gload_lds16(s + (size_t)16 * ldb, d + 512);
  };
  auto FR = [&](const ushort_t* rgn, int rb) -> f16x8 {
    return *(const f16x8*)(rgn + rb * 32 + foff);
  };
  auto VMW = [&]() {
    if constexpr (TERMS == 2) asm volatile("s_waitcnt vmcnt(6)" ::: "memory");
    else                      asm volatile("s_waitcnt vmcnt(4)" ::: "memory");
  };

  // prologue: stage steps 0 and 1
  stA(0, 0); stB(0, 0);
  stA(1, 1); stB(1, 1);
  VMW();                                               // step 0 landed
  asm volatile("s_barrier" ::: "memory");

  for (int t = 0; t < KSTEPS; ++t) {
    const int cb = t % 3, sb = (t + 2) % 3;
    const int ks = (t + 2) & (KSTEPS - 1);             // clamped tail: uniform vmcnt
    stA(sb, ks); stB(sb, ks);                          // issue early (T14)
    const ushort_t* L = lds + cb * BUFE;
    f16x8 rAh[4], rAl[4], rB[8];
#pragma unroll
    for (int i = 0; i < 4; ++i) rAh[i] = FR(L, wr + i * 16);
#pragma unroll
    for (int j = 0; j < 8; ++j) rB[j] = FR(L + BOFF, wc + j * 16);
    if constexpr (TERMS == 2) {
#pragma unroll
      for (int i = 0; i < 4; ++i) rAl[i] = FR(L + ALO, wr + i * 16);
    }
    __builtin_amdgcn_s_setprio(1);
#pragma unroll
    for (int j = 0; j < 8; ++j)
#pragma unroll
      for (int i = 0; i < 4; ++i) acc[i][j] = mfma16h(rAh[i], rB[j], acc[i][j]);
    if constexpr (TERMS == 2) {
#pragma unroll
      for (int j = 0; j < 8; ++j)
#pragma unroll
        for (int i = 0; i < 4; ++i) acc[i][j] = mfma16h(rAl[i], rB[j], acc[i][j]);
    }
    __builtin_amdgcn_s_setprio(0);
    VMW();                                             // step t+1's loads landed
    asm volatile("s_barrier" ::: "memory");
  }
}

// ---------- kernel 1: split t/v/a -> packed fp16 hi|lo + transposed hi ----------
__global__ __launch_bounds__(256) void split_x_kernel(
    const float* __restrict__ v, const float* __restrict__ t, const float* __restrict__ a,
    ushort_t* __restrict__ xpack, ushort_t* __restrict__ xT) {
  __shared__ ushort_t tile[64][65];
  int mod = blockIdx.z;
  const float* src = (mod == 0) ? v : (mod == 1 ? t : a);
  int b = blockIdx.y;
  int s0 = (blockIdx.x >> 4) * 64;
  int f0 = (blockIdx.x & 15) * 64;
  int tid = threadIdx.x;
  ushort_t* xp = xpack + mod * (NX * 2);
  ushort_t* xt = xT + mod * NX;
  int fl = (tid & 15) * 4;
#pragma unroll
  for (int r = 0; r < 4; ++r) {
    int sl = (tid >> 4) + r * 16;
    int row = b * S + s0 + sl;
    float4 x = *(const float4*)(src + (size_t)row * F + f0 + fl);
    ushort_t h0 = f2h(x.x), h1 = f2h(x.y), h2 = f2h(x.z), h3 = f2h(x.w);
    size_t o = pk(row, f0 + fl, XP);
    *(ushort4*)(xp + o) = make_ushort4(h0, h1, h2, h3);
    *(ushort4*)(xp + o + 32) = make_ushort4(
        f2h(x.x - h2f(h0)), f2h(x.y - h2f(h1)),
        f2h(x.z - h2f(h2)), f2h(x.w - h2f(h3)));
    tile[sl][fl] = h0; tile[sl][fl + 1] = h1; tile[sl][fl + 2] = h2; tile[sl][fl + 3] = h3;
  }
  __syncthreads();
#pragma unroll
  for (int r = 0; r < 4; ++r) {
    int flr = (tid >> 4) + r * 16;
    int sl4 = (tid & 15) * 4;
    ushort4 o = make_ushort4(tile[sl4][flr], tile[sl4 + 1][flr],
                             tile[sl4 + 2][flr], tile[sl4 + 3][flr]);
    size_t tidx = ((size_t)(b * F + f0 + flr)) * S + s0 + sl4;
    *(ushort4*)(xt + tidx) = o;
  }
}

// ---------- kernel 2: W (2048x1024) -> WT plain fp16 (1024 rows x K=2048) ----------
__global__ __launch_bounds__(256) void split_w_kernel(
    const float* __restrict__ w0, const float* __restrict__ w1, const float* __restrict__ w2,
    ushort_t* __restrict__ wtpack) {
  __shared__ ushort_t th[64][65];
  int br = blockIdx.z;
  const float* w = (br == 0) ? w0 : (br == 1 ? w1 : w2);
  int g0 = blockIdx.x * 64;
  int f0 = blockIdx.y * 64;
  int tid = threadIdx.x;
  int gl = (tid & 15) * 4;
#pragma unroll
  for (int r = 0; r < 4; ++r) {
    int fl = (tid >> 4) + r * 16;
    float4 x = *(const float4*)(w + (size_t)(f0 + fl) * F + g0 + gl);
    th[fl][gl] = f2h(x.x); th[fl][gl + 1] = f2h(x.y);
    th[fl][gl + 2] = f2h(x.z); th[fl][gl + 3] = f2h(x.w);
  }
  __syncthreads();
  ushort_t* op = wtpack + br * NW;
#pragma unroll
  for (int r = 0; r < 4; ++r) {
    int glr = (tid >> 4) + r * 16;
    int fl4 = (tid & 15) * 4;
    size_t o = (size_t)(g0 + glr) * (2 * F) + f0 + fl4;
    *(ushort4*)(op + o) = make_ushort4(th[fl4][glr], th[fl4 + 1][glr],
                                       th[fl4 + 2][glr], th[fl4 + 3][glr]);
  }
}

// ---------- kernel 3: Feat = tanh(concat(x1,x2) @ W + b), fp16 out ----------
// TERMS=1: reads only the hi halves of the packed x (plain-fp16 accuracy is
// sufficient here; W is already plain fp16, so the A-split added <1.5e-4).
__global__ __launch_bounds__(512, 2) void feat_gemm_kernel(
    const ushort_t* __restrict__ xpack, const ushort_t* __restrict__ wtpack,
    const float* __restrict__ b0, const float* __restrict__ b1, const float* __restrict__ b2,
    ushort_t* __restrict__ fpack) {
  constexpr int M1[3] = {1, 1, 2};   // t, t, a
  constexpr int M2[3] = {0, 2, 0};   // v, a, v
  __shared__ __attribute__((aligned(16))) ushort_t lds[3 * 16384];   // 96 KB
  int br = blockIdx.z;
  int lin = blockIdx.x;              // 0..127
  // XCD-chunked: lin&7 = XCD; the 4 gn-blocks sharing an A-panel-pair sit on
  // the SAME XCD (lin, +32, +64, +96 all have equal lin&7).
  int gm0 = ((lin & 7) * 4 + ((lin >> 3) & 3)) * 256;
  int gn0 = (lin >> 5) * 256;
  int tid = threadIdx.x, lane = tid & 63, w = tid >> 6;
  const ushort_t* a1 = xpack + M1[br] * (NX * 2) + (size_t)gm0 * XP;
  const ushort_t* a2 = xpack + M2[br] * (NX * 2) + (size_t)gm0 * XP;
  const ushort_t* bb = wtpack + br * NW + (size_t)gn0 * (2 * F);
  f32x4 acc[4][8] = {};
  gemm_core<64, 32, 1, 64>(a1, a2, XP, bb, 2 * F, lds, tid, acc);
  const float* bias = (br == 0) ? b0 : (br == 1 ? b1 : b2);
  ushort_t* op = fpack + br * NX;
  int wr = (w >> 1) * 64, wc = (w & 1) * 128;
#pragma unroll
  for (int i = 0; i < 4; ++i)
#pragma unroll
    for (int j = 0; j < 8; ++j)
#pragma unroll
      for (int r = 0; r < 4; ++r) {
        int row = gm0 + wr + i * 16 + (lane >> 4) * 4 + r;
        int col = gn0 + wc + j * 16 + (lane & 15);
        op[(size_t)row * F + col] = f2h(tanhf(acc[i][j][r] + bias[col]));
      }
}

// ---------- kernel 4: scores = q @ feat^T, fp32 out (q kept 2-term split) ----------
__global__ __launch_bounds__(512, 2) void scores_gemm_kernel(
    const ushort_t* __restrict__ xpack, const ushort_t* __restrict__ fpack,
    float* __restrict__ scores) {
  constexpr int QM[3] = {2, 0, 1};   // a, v, t
  __shared__ __attribute__((aligned(16))) ushort_t lds[3 * 24576];
  int z = blockIdx.z;
  int br = z >> 4, b = z & 15;
  int gm0 = blockIdx.x * 256;
  int gn0 = blockIdx.y * 256;
  int tid = threadIdx.x, lane = tid & 63, w = tid >> 6;
  const ushort_t* a1 = xpack + QM[br] * (NX * 2) + (size_t)(b * S + gm0) * XP;
  const ushort_t* bb = fpack + br * NX + (size_t)(b * S + gn0) * F;
  f32x4 acc[4][8] = {};
  gemm_core<32, 32, 2, 64>(a1, a1, XP, bb, F, lds, tid, acc);
  float* out = scores + (size_t)z * S * S;
  int wr = (w >> 1) * 64, wc = (w & 1) * 128;
#pragma unroll
  for (int i = 0; i < 4; ++i)
#pragma unroll
    for (int j = 0; j < 8; ++j)
#pragma unroll
      for (int r = 0; r < 4; ++r) {
        int row = gm0 + wr + i * 16 + (lane >> 4) * 4 + r;
        int col = gn0 + wc + j * 16 + (lane & 15);
        out[(size_t)row * S + col] = acc[i][j][r];
      }
}

// ---------- kernel 5: row softmax (512), fp32 in -> fp16 p ----------
__global__ __launch_bounds__(256) void softmax_kernel(
    const float* __restrict__ scores, ushort_t* __restrict__ p) {
  int wave = threadIdx.x >> 6, lane = threadIdx.x & 63;
  int row = blockIdx.x * 4 + wave;
  const float* src = scores + (size_t)row * S;
  float4 v0 = *(const float4*)(src + lane * 8);
  float4 v1 = *(const float4*)(src + lane * 8 + 4);
  float m = fmaxf(fmaxf(fmaxf(v0.x, v0.y), fmaxf(v0.z, v0.w)),
                  fmaxf(fmaxf(v1.x, v1.y), fmaxf(v1.z, v1.w)));
#pragma unroll
  for (int d = 1; d < 64; d <<= 1) m = fmaxf(m, __shfl_xor(m, d));
  float e[8] = {expf(v0.x - m), expf(v0.y - m), expf(v0.z - m), expf(v0.w - m),
                expf(v1.x - m), expf(v1.y - m), expf(v1.z - m), expf(v1.w - m)};
  float s = ((e[0] + e[1]) + (e[2] + e[3])) + ((e[4] + e[5]) + (e[6] + e[7]));
#pragma unroll
  for (int d = 1; d < 64; d <<= 1) s += __shfl_xor(s, d);
  float inv = 1.0f / s;
  u16x8 o;
#pragma unroll
  for (int j = 0; j < 8; ++j) o[j] = f2h(e[j] * inv);
  *(u16x8*)(p + (size_t)row * S + lane * 8) = o;
}

// ---------- kernel 6: O = (p @ q) * feat, fp32 out ----------
__global__ __launch_bounds__(512, 2) void pv_gemm_kernel(
    const ushort_t* __restrict__ p, const ushort_t* __restrict__ xT,
    const ushort_t* __restrict__ fpack, float* __restrict__ out) {
  constexpr int QM[3] = {2, 0, 1};
  __shared__ __attribute__((aligned(16))) ushort_t lds[3 * 16384];   // 96 KB
  int z = blockIdx.z;
  int br = z >> 4, b = z & 15;
  int gm0 = blockIdx.x * 256;
  int gn0 = blockIdx.y * 256;
  int tid = threadIdx.x, lane = tid & 63, w = tid >> 6;
  const ushort_t* pa = p + (size_t)z * S * S + (size_t)gm0 * S;
  const ushort_t* qt = xT + QM[br] * NX + (size_t)b * F * S + (size_t)gn0 * S;  // [f][s]
  f32x4 acc[4][8] = {};
  gemm_core<16, 16, 1, 32>(pa, pa, S, qt, S, lds, tid, acc);
  const ushort_t* fp = fpack + br * NX;
  int wr = (w >> 1) * 64, wc = (w & 1) * 128;
#pragma unroll
  for (int i = 0; i < 4; ++i)
#pragma unroll
    for (int j = 0; j < 8; ++j)
#pragma unroll
      for (int r = 0; r < 4; ++r) {
        int row = gm0 + wr + i * 16 + (lane >> 4) * 4 + r;
        int col = gn0 + wc + j * 16 + (lane & 15);
        float fe = h2f(fp[(size_t)(b * S + row) * F + col]);
        out[(size_t)(b * S + row) * (3 * F) + br * F + col] = acc[i][j][r] * fe;
      }
}

extern "C" void kernel_launch(void* const* d_in, const int* in_sizes, int n_in,
                              void* d_out, int out_size, void* d_ws, size_t ws_size,
                              hipStream_t stream) {
  (void)in_sizes; (void)n_in; (void)out_size; (void)ws_size;
  const float* v = (const float*)d_in[0];
  const float* t = (const float*)d_in[1];
  const float* a = (const float*)d_in[2];
  const float* W_tv = (const float*)d_in[3];
  const float* b_tv = (const float*)d_in[4];
  const float* W_ta = (const float*)d_in[5];
  const float* b_ta = (const float*)d_in[6];
  const float* W_av = (const float*)d_in[7];
  const float* b_av = (const float*)d_in[8];
  float* out = (float*)d_out;

  // ws layout (~290 MB total)
  ushort_t* xpack = (ushort_t*)d_ws;            // 3 * NX*2 (fp16 hi|lo packed)
  ushort_t* xT = xpack + 3 * (NX * 2);          // 3 * NX (fp16 plain, [f][s])
  ushort_t* wtpack = xT + 3 * NX;               // 3 * NW (fp16 plain)
  ushort_t* fpack = wtpack + 3 * NW;            // 3 * NX (fp16 plain)
  float* scores = (float*)(fpack + 3 * NX);
  ushort_t* pbuf = (ushort_t*)(scores + NSC);

  split_x_kernel<<<dim3(128, 16, 3), 256, 0, stream>>>(v, t, a, xpack, xT);
  split_w_kernel<<<dim3(16, 32, 3), 256, 0, stream>>>(W_tv, W_ta, W_av, wtpack);
  feat_gemm_kernel<<<dim3(128, 1, 3), 512, 0, stream>>>(xpack, wtpack,
                                                        b_tv, b_ta, b_av, fpack);
  scores_gemm_kernel<<<dim3(2, 2, 48), 512, 0, stream>>>(xpack, fpack, scores);
  softmax_kernel<<<dim3((3 * B * S) / 4), 256, 0, stream>>>(scores, pbuf);
  pv_gemm_kernel<<<dim3(2, 4, 48), 512, 0, stream>>>(pbuf, xT, fpack, out);
}